// Round 1
// baseline (1317.508 us; speedup 1.0000x reference)
//
#include <hip/hip_runtime.h>
#include <math.h>

// ---- problem dims ----
constexpr int kF  = 512;
constexpr int kW  = 256;
constexpr int kFW = kF * kW;      // 131072
constexpr int kNH = 8;
constexpr int kDH = 64;

// ---- workspace layout (float offsets) ----
constexpr size_t H_OFF   = 0;                    // [8,512,256]
constexpr size_t SA_OFF  = H_OFF  + 8 * (size_t)kFW;   // [8,512,256]
constexpr size_t CA_OFF  = SA_OFF + 8 * (size_t)kFW;   // [8,512,256]
constexpr size_t Q_OFF   = CA_OFF + 8 * (size_t)kFW;   // [8,512,256]
constexpr size_t K_OFF   = Q_OFF  + 8 * (size_t)kFW;
constexpr size_t V_OFF   = K_OFF  + 8 * (size_t)kFW;
constexpr size_t TMP_OFF = V_OFF  + 8 * (size_t)kFW;   // up to [16,512,256]
constexpr size_t P_OFF   = TMP_OFF + 16 * (size_t)kFW; // [64,256,256] softmax probs
constexpr size_t A_OFF   = P_OFF  + (size_t)64 * 256 * 256; // [8,512,256]
constexpr size_t Z0_OFF  = A_OFF  + 8 * (size_t)kFW;   // [24,2048,256]
constexpr size_t Z2_OFF  = Q_OFF;                      // reuse q/k/v region: [24,512,256]
// total = Z0_OFF + 24*2048*256 = 26,214,400 floats = 100 MB

// ---------------- LayerNorm over feature axis ----------------
__global__ __launch_bounds__(256) void ln_kernel(const float* __restrict__ x,
                                                 const float* __restrict__ g,
                                                 const float* __restrict__ b,
                                                 float* __restrict__ y) {
    int c = blockIdx.x >> 8;          // 8 channels
    int w = blockIdx.x & 255;         // 256 frames
    int tid = threadIdx.x;
    __shared__ float red[256];
    const float* xb = x + (size_t)c * kFW + w;
    float v0 = xb[(size_t)tid * kW];
    float v1 = xb[(size_t)(tid + 256) * kW];
    red[tid] = v0 + v1;
    __syncthreads();
    for (int s = 128; s > 0; s >>= 1) { if (tid < s) red[tid] += red[tid + s]; __syncthreads(); }
    float mu = red[0] * (1.0f / 512.0f);
    __syncthreads();
    float d0 = v0 - mu, d1 = v1 - mu;
    red[tid] = d0 * d0 + d1 * d1;
    __syncthreads();
    for (int s = 128; s > 0; s >>= 1) { if (tid < s) red[tid] += red[tid + s]; __syncthreads(); }
    float rstd = rsqrtf(red[0] * (1.0f / 512.0f) + 1e-5f);
    float* yb = y + (size_t)c * kFW + w;
    yb[(size_t)tid * kW]         = d0 * rstd * g[c * kF + tid]       + b[c * kF + tid];
    yb[(size_t)(tid + 256) * kW] = d1 * rstd * g[c * kF + tid + 256] + b[c * kF + tid + 256];
}

// ---------------- batched per-channel GEMM: Y[c] = PW[c](GxK) * X[c](KxN) ----------------
__global__ __launch_bounds__(256) void gemm_pw(const float* __restrict__ PW,
                                               const float* __restrict__ X,
                                               float* __restrict__ Y,
                                               int G, int K, int N) {
    int c = blockIdx.z;
    const float* A = PW + (size_t)c * G * K;   // row-major [G,K]
    const float* B = X  + (size_t)c * K * N;   // row-major [K,N]
    float* Cp      = Y  + (size_t)c * G * N;
    int bm = blockIdx.y * 64, bn = blockIdx.x * 64;
    __shared__ float As[16][65];
    __shared__ float Bs[16][65];
    int tid = threadIdx.x;
    int tm = (tid >> 4) << 2;
    int tn = (tid & 15) << 2;
    float acc[4][4] = {{0.f}};
    for (int k0 = 0; k0 < K; k0 += 16) {
        int ka = tid & 15, ma = tid >> 4;
        #pragma unroll
        for (int i = 0; i < 4; i++)
            As[ka][ma + i * 16] = A[(size_t)(bm + ma + i * 16) * K + k0 + ka];
        int nb = tid & 63, kb = tid >> 6;
        #pragma unroll
        for (int i = 0; i < 4; i++)
            Bs[kb + i * 4][nb] = B[(size_t)(k0 + kb + i * 4) * N + bn + nb];
        __syncthreads();
        #pragma unroll
        for (int kk = 0; kk < 16; kk++) {
            float av[4], bv[4];
            #pragma unroll
            for (int i = 0; i < 4; i++) av[i] = As[kk][tm + i];
            #pragma unroll
            for (int j = 0; j < 4; j++) bv[j] = Bs[kk][tn + j];
            #pragma unroll
            for (int i = 0; i < 4; i++)
                #pragma unroll
                for (int j = 0; j < 4; j++) acc[i][j] += av[i] * bv[j];
        }
        __syncthreads();
    }
    #pragma unroll
    for (int i = 0; i < 4; i++)
        #pragma unroll
        for (int j = 0; j < 4; j++)
            Cp[(size_t)(bm + tm + i) * N + bn + tn + j] = acc[i][j];
}

// ---------------- frame conv (1,3) + channel mix 8->8, + bias ----------------
__global__ __launch_bounds__(256) void conv_mix(const float* __restrict__ x,
                                                const float* __restrict__ cw,
                                                const float* __restrict__ cb,
                                                float* __restrict__ y) {
    __shared__ float scw[192];
    __shared__ float scb[8];
    int tid = threadIdx.x;
    if (tid < 192) scw[tid] = cw[tid];
    if (tid < 8)   scb[tid] = cb[tid];
    __syncthreads();
    int idx = blockIdx.x * 256 + tid;   // over F*W
    int w = idx & 255;
    float acc[8];
    #pragma unroll
    for (int o = 0; o < 8; o++) acc[o] = scb[o];
    #pragma unroll
    for (int i = 0; i < 8; i++) {
        float xm = (w > 0)   ? x[(size_t)i * kFW + idx - 1] : 0.f;
        float x0 =             x[(size_t)i * kFW + idx];
        float xp = (w < 255) ? x[(size_t)i * kFW + idx + 1] : 0.f;
        #pragma unroll
        for (int o = 0; o < 8; o++) {
            const float* wp = &scw[(o * 8 + i) * 3];
            acc[o] += wp[0] * xm + wp[1] * x0 + wp[2] * xp;
        }
    }
    #pragma unroll
    for (int o = 0; o < 8; o++) y[(size_t)o * kFW + idx] = acc[o];
}

// ---------------- channel mix 16->8 ----------------
__global__ __launch_bounds__(256) void mix16to8(const float* __restrict__ x,
                                                const float* __restrict__ dw,
                                                float* __restrict__ y) {
    __shared__ float sdw[128];
    int tid = threadIdx.x;
    if (tid < 128) sdw[tid] = dw[tid];
    __syncthreads();
    int idx = blockIdx.x * 256 + tid;
    float xv[16];
    #pragma unroll
    for (int cc = 0; cc < 16; cc++) xv[cc] = x[(size_t)cc * kFW + idx];
    #pragma unroll
    for (int o = 0; o < 8; o++) {
        float s = 0.f;
        #pragma unroll
        for (int cc = 0; cc < 16; cc++) s += sdw[o * 16 + cc] * xv[cc];
        y[(size_t)o * kFW + idx] = s;
    }
}

// ---------------- QK^T (scaled), batched over (c,h) ----------------
__global__ __launch_bounds__(256) void qk_kernel(const float* __restrict__ q,
                                                 const float* __restrict__ kmat,
                                                 float* __restrict__ out) {
    int ch = blockIdx.z;               // c*8 + h
    int c = ch >> 3, h = ch & 7;
    const float* qb = q    + (size_t)c * kFW + (size_t)h * kDH * kW;  // [64 d][256 wq], d-stride kW
    const float* kb = kmat + (size_t)c * kFW + (size_t)h * kDH * kW;
    float* ob = out + (size_t)ch * kW * kW;
    int bm = blockIdx.y * 64, bn = blockIdx.x * 64;
    __shared__ float As[16][65], Bs[16][65];
    int tid = threadIdx.x;
    int tm = (tid >> 4) << 2, tn = (tid & 15) << 2;
    float acc[4][4] = {{0.f}};
    for (int k0 = 0; k0 < kDH; k0 += 16) {
        int m = tid & 63, k4 = tid >> 6;
        #pragma unroll
        for (int i = 0; i < 4; i++) {
            As[k4 + i * 4][m] = qb[(size_t)(k0 + k4 + i * 4) * kW + bm + m];
            Bs[k4 + i * 4][m] = kb[(size_t)(k0 + k4 + i * 4) * kW + bn + m];
        }
        __syncthreads();
        #pragma unroll
        for (int kk = 0; kk < 16; kk++) {
            float av[4], bv[4];
            #pragma unroll
            for (int i = 0; i < 4; i++) av[i] = As[kk][tm + i];
            #pragma unroll
            for (int j = 0; j < 4; j++) bv[j] = Bs[kk][tn + j];
            #pragma unroll
            for (int i = 0; i < 4; i++)
                #pragma unroll
                for (int j = 0; j < 4; j++) acc[i][j] += av[i] * bv[j];
        }
        __syncthreads();
    }
    const float scale = 0.044194173824159216f;  // 1/sqrt(512)
    #pragma unroll
    for (int i = 0; i < 4; i++)
        #pragma unroll
        for (int j = 0; j < 4; j++)
            ob[(size_t)(bm + tm + i) * kW + bn + tn + j] = acc[i][j] * scale;
}

// ---------------- row softmax over 256 ----------------
__global__ __launch_bounds__(256) void softmax_kernel(const float* __restrict__ s,
                                                      float* __restrict__ p) {
    int r = blockIdx.x;
    int tid = threadIdx.x;
    __shared__ float red[256];
    float v = s[(size_t)r * 256 + tid];
    red[tid] = v;
    __syncthreads();
    for (int st = 128; st > 0; st >>= 1) { if (tid < st) red[tid] = fmaxf(red[tid], red[tid + st]); __syncthreads(); }
    float mx = red[0];
    __syncthreads();
    float e = expf(v - mx);
    red[tid] = e;
    __syncthreads();
    for (int st = 128; st > 0; st >>= 1) { if (tid < st) red[tid] += red[tid + st]; __syncthreads(); }
    p[(size_t)r * 256 + tid] = e / red[0];
}

// ---------------- P·V, batched over (c,h); writes [c, h*64+d, wq] layout ----------------
__global__ __launch_bounds__(256) void pv_kernel(const float* __restrict__ p,
                                                 const float* __restrict__ v,
                                                 float* __restrict__ a) {
    int ch = blockIdx.z;
    int c = ch >> 3, h = ch & 7;
    const float* Pb = p + (size_t)ch * 65536;                       // [256 wq][256 wk]
    const float* Vb = v + (size_t)c * kFW + (size_t)h * kDH * kW;   // [64 d][256 wk]
    float* Ab       = a + (size_t)c * kFW + (size_t)h * kDH * kW;
    int bm = blockIdx.x * 64;   // wq tile; n covers all 64 d
    __shared__ float As[16][65], Bs[16][65];
    int tid = threadIdx.x;
    int tm = (tid >> 4) << 2, tn = (tid & 15) << 2;
    float acc[4][4] = {{0.f}};
    for (int k0 = 0; k0 < 256; k0 += 16) {
        int kk = tid & 15, mm = tid >> 4;
        #pragma unroll
        for (int i = 0; i < 4; i++) {
            As[kk][mm + i * 16] = Pb[(size_t)(bm + mm + i * 16) * 256 + k0 + kk];
            Bs[kk][mm + i * 16] = Vb[(size_t)(mm + i * 16) * kW + k0 + kk];
        }
        __syncthreads();
        #pragma unroll
        for (int kk2 = 0; kk2 < 16; kk2++) {
            float av[4], bv[4];
            #pragma unroll
            for (int i = 0; i < 4; i++) av[i] = As[kk2][tm + i];
            #pragma unroll
            for (int j = 0; j < 4; j++) bv[j] = Bs[kk2][tn + j];
            #pragma unroll
            for (int i = 0; i < 4; i++)
                #pragma unroll
                for (int j = 0; j < 4; j++) acc[i][j] += av[i] * bv[j];
        }
        __syncthreads();
    }
    #pragma unroll
    for (int i = 0; i < 4; i++)
        #pragma unroll
        for (int j = 0; j < 4; j++)
            Ab[(size_t)(tn + j) * kW + bm + tm + i] = acc[i][j];
}

// ---------------- FFN1 channel mix 24->24 + exact GELU, in place ----------------
__global__ __launch_bounds__(256) void gelu_mix24(float* __restrict__ z,
                                                  const float* __restrict__ dw) {
    __shared__ float sdw[576];
    int tid = threadIdx.x;
    for (int i = tid; i < 576; i += 256) sdw[i] = dw[i];
    __syncthreads();
    size_t idx = (size_t)blockIdx.x * 256 + tid;      // over 2048*256
    const size_t CH = (size_t)2048 * 256;
    float xv[24];
    #pragma unroll
    for (int cc = 0; cc < 24; cc++) xv[cc] = z[cc * CH + idx];
    #pragma unroll
    for (int o = 0; o < 24; o++) {
        float s = 0.f;
        #pragma unroll
        for (int cc = 0; cc < 24; cc++) s += sdw[o * 24 + cc] * xv[cc];
        s = 0.5f * s * (1.0f + erff(s * 0.7071067811865475f));
        z[o * CH + idx] = s;
    }
}

// ---------------- FFN2 channel mix 24->8 + residual add ----------------
__global__ __launch_bounds__(256) void final_mix_add(const float* __restrict__ x,
                                                     const float* __restrict__ z2,
                                                     const float* __restrict__ dw,
                                                     float* __restrict__ out) {
    __shared__ float sdw[192];
    int tid = threadIdx.x;
    if (tid < 192) sdw[tid] = dw[tid];
    __syncthreads();
    int idx = blockIdx.x * 256 + tid;   // over F*W
    float xv[24];
    #pragma unroll
    for (int cc = 0; cc < 24; cc++) xv[cc] = z2[(size_t)cc * kFW + idx];
    #pragma unroll
    for (int o = 0; o < 8; o++) {
        float s = 0.f;
        #pragma unroll
        for (int cc = 0; cc < 24; cc++) s += sdw[o * 24 + cc] * xv[cc];
        out[(size_t)o * kFW + idx] = x[(size_t)o * kFW + idx] + s;
    }
}

extern "C" void kernel_launch(void* const* d_in, const int* in_sizes, int n_in,
                              void* d_out, int out_size, void* d_ws, size_t ws_size,
                              hipStream_t stream) {
    const float* x       = (const float*)d_in[0];
    const float* src     = (const float*)d_in[1];
    const float* ln_g    = (const float*)d_in[2];
    const float* ln_b    = (const float*)d_in[3];
    const float* sa_q_pw = (const float*)d_in[4];
    const float* sa_q_cw = (const float*)d_in[5];
    const float* sa_q_cb = (const float*)d_in[6];
    const float* sa_k_pw = (const float*)d_in[7];
    const float* sa_k_cw = (const float*)d_in[8];
    const float* sa_k_cb = (const float*)d_in[9];
    const float* sa_v_pw = (const float*)d_in[10];
    const float* sa_v_cw = (const float*)d_in[11];
    const float* sa_v_cb = (const float*)d_in[12];
    const float* sa_o_pw = (const float*)d_in[13];
    const float* ca_q_pw = (const float*)d_in[14];
    const float* ca_q_dw = (const float*)d_in[15];
    const float* ca_q_cw = (const float*)d_in[16];
    const float* ca_q_cb = (const float*)d_in[17];
    const float* ca_k_pw = (const float*)d_in[18];
    const float* ca_k_cw = (const float*)d_in[19];
    const float* ca_k_cb = (const float*)d_in[20];
    const float* ca_v_pw = (const float*)d_in[21];
    const float* ca_v_cw = (const float*)d_in[22];
    const float* ca_v_cb = (const float*)d_in[23];
    const float* ca_o_pw = (const float*)d_in[24];
    const float* ffn1_pw = (const float*)d_in[25];
    const float* ffn1_dw = (const float*)d_in[26];
    const float* ffn2_pw = (const float*)d_in[27];
    const float* ffn2_dw = (const float*)d_in[28];

    float* out  = (float*)d_out;
    float* qk1o = out + 1048576;                 // [8,8,256,256]
    float* qk2o = out + 1048576 + 4194304;

    float* ws = (float*)d_ws;
    float* h   = ws + H_OFF;
    float* sa  = ws + SA_OFF;
    float* ca  = ws + CA_OFF;
    float* q   = ws + Q_OFF;
    float* kbf = ws + K_OFF;
    float* vbf = ws + V_OFF;
    float* tmp = ws + TMP_OFF;
    float* p   = ws + P_OFF;
    float* abf = ws + A_OFF;
    float* z0  = ws + Z0_OFF;
    float* z2  = ws + Z2_OFF;

    dim3 blk(256);
    dim3 gemm8(4, 8, 8);     // N=256/64, G=512/64, 8 channels
    dim3 gemm16(4, 8, 16);
    dim3 gemmF1(4, 32, 24);  // G=2048
    dim3 gemmF2(4, 8, 24);   // K=2048
    dim3 gqk(4, 4, 64);
    dim3 gpv(4, 1, 64);

    // h = LayerNorm(x)
    ln_kernel<<<2048, blk, 0, stream>>>(x, ln_g, ln_b, h);

    // ---- self attention ----
    gemm_pw<<<gemm8, blk, 0, stream>>>(sa_q_pw, h, tmp, 512, 512, 256);
    conv_mix<<<512, blk, 0, stream>>>(tmp, sa_q_cw, sa_q_cb, q);
    gemm_pw<<<gemm8, blk, 0, stream>>>(sa_k_pw, h, tmp, 512, 512, 256);
    conv_mix<<<512, blk, 0, stream>>>(tmp, sa_k_cw, sa_k_cb, kbf);
    gemm_pw<<<gemm8, blk, 0, stream>>>(sa_v_pw, h, tmp, 512, 512, 256);
    conv_mix<<<512, blk, 0, stream>>>(tmp, sa_v_cw, sa_v_cb, vbf);
    qk_kernel<<<gqk, blk, 0, stream>>>(q, kbf, qk1o);
    softmax_kernel<<<16384, blk, 0, stream>>>(qk1o, p);
    pv_kernel<<<gpv, blk, 0, stream>>>(p, vbf, abf);
    gemm_pw<<<gemm8, blk, 0, stream>>>(sa_o_pw, abf, sa, 512, 512, 256);

    // ---- cross attention ----
    // xq = [h; sa] is contiguous at ws (16 channels)
    gemm_pw<<<gemm16, blk, 0, stream>>>(ca_q_pw, h, tmp, 512, 512, 256);
    mix16to8<<<512, blk, 0, stream>>>(tmp, ca_q_dw, abf);
    conv_mix<<<512, blk, 0, stream>>>(abf, ca_q_cw, ca_q_cb, q);
    gemm_pw<<<gemm8, blk, 0, stream>>>(ca_k_pw, src, tmp, 512, 512, 256);
    conv_mix<<<512, blk, 0, stream>>>(tmp, ca_k_cw, ca_k_cb, kbf);
    gemm_pw<<<gemm8, blk, 0, stream>>>(ca_v_pw, src, tmp, 512, 512, 256);
    conv_mix<<<512, blk, 0, stream>>>(tmp, ca_v_cw, ca_v_cb, vbf);
    qk_kernel<<<gqk, blk, 0, stream>>>(q, kbf, qk2o);
    softmax_kernel<<<16384, blk, 0, stream>>>(qk2o, p);
    pv_kernel<<<gpv, blk, 0, stream>>>(p, vbf, abf);
    gemm_pw<<<gemm8, blk, 0, stream>>>(ca_o_pw, abf, ca, 512, 512, 256);

    // ---- FFN ----
    // xf = [h; sa; ca] contiguous at ws (24 channels)
    gemm_pw<<<gemmF1, blk, 0, stream>>>(ffn1_pw, h, z0, 2048, 512, 256);
    gelu_mix24<<<2048, blk, 0, stream>>>(z0, ffn1_dw);
    gemm_pw<<<gemmF2, blk, 0, stream>>>(ffn2_pw, z0, z2, 512, 2048, 256);
    final_mix_add<<<512, blk, 0, stream>>>(x, z2, ffn2_dw, out);
}

// Round 2
// 491.540 us; speedup vs baseline: 2.6804x; 2.6804x over previous
//
#include <hip/hip_runtime.h>
#include <math.h>

typedef __attribute__((ext_vector_type(4))) float f32x4;
typedef __attribute__((ext_vector_type(8))) short s16x8;
typedef __attribute__((ext_vector_type(4))) short s16x4;

__device__ __forceinline__ unsigned short f2b(float f) {
    union { float f; unsigned u; } v; v.f = f;
    unsigned r = v.u + 0x7fffu + ((v.u >> 16) & 1u);
    return (unsigned short)(r >> 16);
}
__device__ __forceinline__ float b2f(unsigned short u) {
    union { unsigned u; float f; } v; v.u = ((unsigned)u) << 16;
    return v.f;
}

// ---- dims ----
constexpr int kF = 512;
constexpr int kW = 256;
constexpr int kFW = kF * kW;   // 131072

// ================= LayerNorm over f, output transposed bf16 [c][w][f] ==========
__global__ __launch_bounds__(256) void ln_t_kernel(const float* __restrict__ x,
                                                   const float* __restrict__ g,
                                                   const float* __restrict__ b,
                                                   unsigned short* __restrict__ hTb) {
    int c = blockIdx.x >> 2;
    int w0 = (blockIdx.x & 3) * 64;
    int t = threadIdx.x;
    int wi = t & 63, fg = t >> 6;          // fg: 0..3, f-range fg*128..+127
    const float* xb = x + (size_t)c * kFW + w0 + wi;
    float sum = 0.f, sum2 = 0.f;
    for (int j = 0; j < 128; ++j) {
        float v = xb[(size_t)(fg * 128 + j) * kW];
        sum += v; sum2 += v * v;
    }
    __shared__ float s1[4][64], s2[4][64];
    s1[fg][wi] = sum; s2[fg][wi] = sum2;
    __syncthreads();
    float ts = s1[0][wi] + s1[1][wi] + s1[2][wi] + s1[3][wi];
    float tq = s2[0][wi] + s2[1][wi] + s2[2][wi] + s2[3][wi];
    float mu = ts * (1.0f / 512.0f);
    float rstd = rsqrtf(tq * (1.0f / 512.0f) - mu * mu + 1e-5f);
    const float* gc = g + c * kF + fg * 128;
    const float* bc = b + c * kF + fg * 128;
    unsigned short* ob = hTb + (size_t)c * kFW + (size_t)(w0 + wi) * kF + fg * 128;
    for (int j = 0; j < 128; j += 4) {
        float v0 = xb[(size_t)(fg * 128 + j + 0) * kW];
        float v1 = xb[(size_t)(fg * 128 + j + 1) * kW];
        float v2 = xb[(size_t)(fg * 128 + j + 2) * kW];
        float v3 = xb[(size_t)(fg * 128 + j + 3) * kW];
        s16x4 p = { (short)f2b((v0 - mu) * rstd * gc[j + 0] + bc[j + 0]),
                    (short)f2b((v1 - mu) * rstd * gc[j + 1] + bc[j + 1]),
                    (short)f2b((v2 - mu) * rstd * gc[j + 2] + bc[j + 2]),
                    (short)f2b((v3 - mu) * rstd * gc[j + 3] + bc[j + 3]) };
        *(s16x4*)(&ob[j]) = p;
    }
}

// ================= transpose + cvt: [c][f][w] f32 -> [c][w][f] bf16 ============
__global__ __launch_bounds__(256) void tcvt_kernel(const float* __restrict__ in,
                                                   unsigned short* __restrict__ out) {
    int c = blockIdx.x, f0 = blockIdx.y * 64, w0 = blockIdx.z * 64;
    __shared__ float tile[64][65];
    int t = threadIdx.x;
    int tw = t & 63, tf4 = t >> 6;
    for (int i = 0; i < 16; ++i) {
        int f = tf4 * 16 + i;
        tile[f][tw] = in[(size_t)c * kFW + (size_t)(f0 + f) * kW + w0 + tw];
    }
    __syncthreads();
    int w = t >> 2, fc = (t & 3) * 16;
    unsigned short* ob = out + (size_t)c * kFW + (size_t)(w0 + w) * kF + f0 + fc;
    for (int j = 0; j < 16; j += 4) {
        s16x4 p = { (short)f2b(tile[fc + j + 0][w]), (short)f2b(tile[fc + j + 1][w]),
                    (short)f2b(tile[fc + j + 2][w]), (short)f2b(tile[fc + j + 3][w]) };
        *(s16x4*)(&ob[j]) = p;
    }
}

// ================= unified MFMA GEMM =========================================
// Y[m][n] = sum_k A[m][k] * B^T-source[n][k]   (B given as [n][k] rows, bf16)
// A: fp32 [m][k] (converted on the fly) or bf16 [m][k]
// OMODE: 0 = C f32 [m][n], 1 = C bf16 [m][n], 2 = C bf16 transposed [n][m]
template<bool AF32, int OMODE, int BN>
__global__ __launch_bounds__(256) void gemm_mfma(
    const void* __restrict__ Av, const unsigned short* __restrict__ B,
    void* __restrict__ Cv,
    int M, int N, int K,
    long a_hi, long a_lo, long b_hi, long b_lo, long c_hi, long c_lo,
    int bshift, int a_rs, int b_rs, int c_rs, float scale)
{
    constexpr int NF = BN / 64;          // n-fragments per wave
    constexpr int WN = BN / 4;           // n-columns per wave
    __shared__ unsigned char lds[8192 + BN * 128];

    int t = threadIdx.x;
    int lane = t & 63, wv = t >> 6;
    int l16 = lane & 15, l4 = lane >> 4;
    int swz = (lane & 7) << 4;

    int by = blockIdx.y;
    int bhi = by >> bshift, blo = by & ((1 << bshift) - 1);
    int ntiles = N / BN;
    int bm = (blockIdx.x / ntiles) * 64;
    int bn = (blockIdx.x % ntiles) * BN;

    const unsigned short* Bp = B + (size_t)bhi * b_hi + (size_t)blo * b_lo + (size_t)bn * b_rs;

    f32x4 acc[4][NF];
    #pragma unroll
    for (int i = 0; i < 4; ++i)
        #pragma unroll
        for (int j = 0; j < NF; ++j) acc[i][j] = (f32x4){0.f, 0.f, 0.f, 0.f};

    for (int k0 = 0; k0 < K; k0 += 64) {
        if constexpr (AF32) {
            const float* A = (const float*)Av + (size_t)bhi * a_hi + (size_t)blo * a_lo;
            #pragma unroll
            for (int it = 0; it < 4; ++it) {
                int idx = it * 256 + t;
                int r = idx >> 4, c4 = idx & 15;
                f32x4 v = *(const f32x4*)(A + (size_t)(bm + r) * a_rs + k0 + c4 * 4);
                s16x4 pk = { (short)f2b(v.x), (short)f2b(v.y), (short)f2b(v.z), (short)f2b(v.w) };
                int off = r * 128 + ((c4 * 8) ^ ((r & 7) << 4));
                *(s16x4*)(&lds[off]) = pk;
            }
        } else {
            const unsigned short* A = (const unsigned short*)Av + (size_t)bhi * a_hi + (size_t)blo * a_lo;
            #pragma unroll
            for (int it = 0; it < 2; ++it) {
                int idx = it * 256 + t;
                int r = idx >> 3, ck = idx & 7;
                s16x8 v = *(const s16x8*)(A + (size_t)(bm + r) * a_rs + k0 + ck * 8);
                int off = r * 128 + ((ck * 16) ^ ((r & 7) << 4));
                *(s16x8*)(&lds[off]) = v;
            }
        }
        #pragma unroll
        for (int it = 0; it < BN / 32; ++it) {
            int idx = it * 256 + t;
            int r = idx >> 3, ck = idx & 7;
            s16x8 v = *(const s16x8*)(Bp + (size_t)r * b_rs + k0 + ck * 8);
            int off = 8192 + r * 128 + ((ck * 16) ^ ((r & 7) << 4));
            *(s16x8*)(&lds[off]) = v;
        }
        __syncthreads();
        #pragma unroll
        for (int ks = 0; ks < 2; ++ks) {
            s16x8 af[4], bfr[NF];
            #pragma unroll
            for (int mi = 0; mi < 4; ++mi)
                af[mi] = *(const s16x8*)(&lds[(mi * 16 + l16) * 128 + ((ks * 64 + l4 * 16) ^ swz)]);
            #pragma unroll
            for (int ni = 0; ni < NF; ++ni)
                bfr[ni] = *(const s16x8*)(&lds[8192 + (wv * WN + ni * 16 + l16) * 128 + ((ks * 64 + l4 * 16) ^ swz)]);
            #pragma unroll
            for (int mi = 0; mi < 4; ++mi)
                #pragma unroll
                for (int ni = 0; ni < NF; ++ni)
                    acc[mi][ni] = __builtin_amdgcn_mfma_f32_16x16x32_bf16(af[mi], bfr[ni], acc[mi][ni], 0, 0, 0);
        }
        __syncthreads();
    }

    if constexpr (OMODE == 0) {
        float* C = (float*)Cv + (size_t)bhi * c_hi + (size_t)blo * c_lo;
        #pragma unroll
        for (int mi = 0; mi < 4; ++mi)
            #pragma unroll
            for (int ni = 0; ni < NF; ++ni) {
                int n = bn + wv * WN + ni * 16 + l16;
                int m0 = bm + mi * 16 + l4 * 4;
                #pragma unroll
                for (int r = 0; r < 4; ++r)
                    C[(size_t)(m0 + r) * c_rs + n] = acc[mi][ni][r] * scale;
            }
    } else if constexpr (OMODE == 1) {
        unsigned short* C = (unsigned short*)Cv + (size_t)bhi * c_hi + (size_t)blo * c_lo;
        #pragma unroll
        for (int mi = 0; mi < 4; ++mi)
            #pragma unroll
            for (int ni = 0; ni < NF; ++ni) {
                int n = bn + wv * WN + ni * 16 + l16;
                int m0 = bm + mi * 16 + l4 * 4;
                #pragma unroll
                for (int r = 0; r < 4; ++r)
                    C[(size_t)(m0 + r) * c_rs + n] = f2b(acc[mi][ni][r] * scale);
            }
    } else {
        unsigned short* C = (unsigned short*)Cv + (size_t)bhi * c_hi + (size_t)blo * c_lo;
        #pragma unroll
        for (int mi = 0; mi < 4; ++mi)
            #pragma unroll
            for (int ni = 0; ni < NF; ++ni) {
                int n = bn + wv * WN + ni * 16 + l16;
                int m0 = bm + mi * 16 + l4 * 4;
                s16x4 pk = { (short)f2b(acc[mi][ni][0] * scale), (short)f2b(acc[mi][ni][1] * scale),
                             (short)f2b(acc[mi][ni][2] * scale), (short)f2b(acc[mi][ni][3] * scale) };
                *(s16x4*)(&C[(size_t)n * c_rs + m0]) = pk;
            }
    }
}

// ================= conv (1,3) + 8->8 channel mix, T layout [c][w][f] ==========
__global__ __launch_bounds__(256) void conv_t_kernel(const unsigned short* __restrict__ in,
                                                     const float* __restrict__ cw,
                                                     const float* __restrict__ cb,
                                                     unsigned short* __restrict__ out) {
    __shared__ float scw[192]; __shared__ float scb[8];
    int t = threadIdx.x;
    if (t < 192) scw[t] = cw[t];
    if (t < 8)   scb[t] = cb[t];
    __syncthreads();
    int gi = blockIdx.x * 256 + t;
    int w = gi >> 9;
    float acc[8];
    #pragma unroll
    for (int o = 0; o < 8; ++o) acc[o] = scb[o];
    #pragma unroll
    for (int i = 0; i < 8; ++i) {
        size_t base = (size_t)i * kFW + gi;
        float xm = (w > 0)   ? b2f(in[base - 512]) : 0.f;
        float x0 =             b2f(in[base]);
        float xp = (w < 255) ? b2f(in[base + 512]) : 0.f;
        #pragma unroll
        for (int o = 0; o < 8; ++o) {
            const float* wp = &scw[(o * 8 + i) * 3];
            acc[o] += wp[0] * xm + wp[1] * x0 + wp[2] * xp;
        }
    }
    #pragma unroll
    for (int o = 0; o < 8; ++o) out[(size_t)o * kFW + gi] = f2b(acc[o]);
}

// ================= conv (1,3) + mix, N layout [c][f][w] (V branch) ============
__global__ __launch_bounds__(256) void conv_n_kernel(const unsigned short* __restrict__ in,
                                                     const float* __restrict__ cw,
                                                     const float* __restrict__ cb,
                                                     unsigned short* __restrict__ out) {
    __shared__ float scw[192]; __shared__ float scb[8];
    int t = threadIdx.x;
    if (t < 192) scw[t] = cw[t];
    if (t < 8)   scb[t] = cb[t];
    __syncthreads();
    int gi = blockIdx.x * 256 + t;
    int w = gi & 255;
    float acc[8];
    #pragma unroll
    for (int o = 0; o < 8; ++o) acc[o] = scb[o];
    #pragma unroll
    for (int i = 0; i < 8; ++i) {
        size_t base = (size_t)i * kFW + gi;
        float xm = (w > 0)   ? b2f(in[base - 1]) : 0.f;
        float x0 =             b2f(in[base]);
        float xp = (w < 255) ? b2f(in[base + 1]) : 0.f;
        #pragma unroll
        for (int o = 0; o < 8; ++o) {
            const float* wp = &scw[(o * 8 + i) * 3];
            acc[o] += wp[0] * xm + wp[1] * x0 + wp[2] * xp;
        }
    }
    #pragma unroll
    for (int o = 0; o < 8; ++o) out[(size_t)o * kFW + gi] = f2b(acc[o]);
}

// ================= 16->8 channel mix, T layout ================================
__global__ __launch_bounds__(256) void mix16to8_t_kernel(const unsigned short* __restrict__ in,
                                                         const float* __restrict__ dw,
                                                         unsigned short* __restrict__ out) {
    __shared__ float sdw[128];
    int t = threadIdx.x;
    if (t < 128) sdw[t] = dw[t];
    __syncthreads();
    int gi = blockIdx.x * 256 + t;
    float xv[16];
    #pragma unroll
    for (int cc = 0; cc < 16; ++cc) xv[cc] = b2f(in[(size_t)cc * kFW + gi]);
    #pragma unroll
    for (int o = 0; o < 8; ++o) {
        float s = 0.f;
        #pragma unroll
        for (int cc = 0; cc < 16; ++cc) s += sdw[o * 16 + cc] * xv[cc];
        out[(size_t)o * kFW + gi] = f2b(s);
    }
}

// ================= row softmax over 256, bf16 out =============================
__global__ __launch_bounds__(256) void softmax_kernel(const float* __restrict__ s,
                                                      unsigned short* __restrict__ p) {
    int r = blockIdx.x;
    int tid = threadIdx.x;
    __shared__ float red[256];
    float v = s[(size_t)r * 256 + tid];
    red[tid] = v;
    __syncthreads();
    for (int st = 128; st > 0; st >>= 1) { if (tid < st) red[tid] = fmaxf(red[tid], red[tid + st]); __syncthreads(); }
    float mx = red[0];
    __syncthreads();
    float e = expf(v - mx);
    red[tid] = e;
    __syncthreads();
    for (int st = 128; st > 0; st >>= 1) { if (tid < st) red[tid] += red[tid + st]; __syncthreads(); }
    p[(size_t)r * 256 + tid] = f2b(e / red[0]);
}

// ================= FFN1: 24->24 mix + exact GELU, T layout =====================
__global__ __launch_bounds__(256) void gelu24_kernel(const unsigned short* __restrict__ in,
                                                     const float* __restrict__ dw,
                                                     unsigned short* __restrict__ out) {
    __shared__ float sdw[576];
    int t = threadIdx.x;
    for (int i = t; i < 576; i += 256) sdw[i] = dw[i];
    __syncthreads();
    size_t gi = (size_t)blockIdx.x * 256 + t;    // over 256*2048
    const size_t CH = (size_t)256 * 2048;
    float xv[24];
    #pragma unroll
    for (int cc = 0; cc < 24; ++cc) xv[cc] = b2f(in[cc * CH + gi]);
    #pragma unroll
    for (int o = 0; o < 24; ++o) {
        float s = 0.f;
        #pragma unroll
        for (int cc = 0; cc < 24; ++cc) s += sdw[o * 24 + cc] * xv[cc];
        s = 0.5f * s * (1.0f + erff(s * 0.7071067811865475f));
        out[o * CH + gi] = f2b(s);
    }
}

// ================= FFN2: 24->8 mix + residual ================================
__global__ __launch_bounds__(256) void final_mix_add(const float* __restrict__ x,
                                                     const float* __restrict__ z2,
                                                     const float* __restrict__ dw,
                                                     float* __restrict__ out) {
    __shared__ float sdw[192];
    int t = threadIdx.x;
    if (t < 192) sdw[t] = dw[t];
    __syncthreads();
    int gi = blockIdx.x * 256 + t;
    float xv[24];
    #pragma unroll
    for (int cc = 0; cc < 24; ++cc) xv[cc] = z2[(size_t)cc * kFW + gi];
    #pragma unroll
    for (int o = 0; o < 8; ++o) {
        float s = 0.f;
        #pragma unroll
        for (int cc = 0; cc < 24; ++cc) s += sdw[o * 24 + cc] * xv[cc];
        out[(size_t)o * kFW + gi] = x[(size_t)o * kFW + gi] + s;
    }
}

// ================= launch =====================================================
extern "C" void kernel_launch(void* const* d_in, const int* in_sizes, int n_in,
                              void* d_out, int out_size, void* d_ws, size_t ws_size,
                              hipStream_t stream) {
    const float* x       = (const float*)d_in[0];
    const float* src     = (const float*)d_in[1];
    const float* ln_g    = (const float*)d_in[2];
    const float* ln_b    = (const float*)d_in[3];
    const float* sa_q_pw = (const float*)d_in[4];
    const float* sa_q_cw = (const float*)d_in[5];
    const float* sa_q_cb = (const float*)d_in[6];
    const float* sa_k_pw = (const float*)d_in[7];
    const float* sa_k_cw = (const float*)d_in[8];
    const float* sa_k_cb = (const float*)d_in[9];
    const float* sa_v_pw = (const float*)d_in[10];
    const float* sa_v_cw = (const float*)d_in[11];
    const float* sa_v_cb = (const float*)d_in[12];
    const float* sa_o_pw = (const float*)d_in[13];
    const float* ca_q_pw = (const float*)d_in[14];
    const float* ca_q_dw = (const float*)d_in[15];
    const float* ca_q_cw = (const float*)d_in[16];
    const float* ca_q_cb = (const float*)d_in[17];
    const float* ca_k_pw = (const float*)d_in[18];
    const float* ca_k_cw = (const float*)d_in[19];
    const float* ca_k_cb = (const float*)d_in[20];
    const float* ca_v_pw = (const float*)d_in[21];
    const float* ca_v_cw = (const float*)d_in[22];
    const float* ca_v_cb = (const float*)d_in[23];
    const float* ca_o_pw = (const float*)d_in[24];
    const float* ffn1_pw = (const float*)d_in[25];
    const float* ffn1_dw = (const float*)d_in[26];
    const float* ffn2_pw = (const float*)d_in[27];
    const float* ffn2_dw = (const float*)d_in[28];

    float* out  = (float*)d_out;
    float* qk1o = out + 1048576;
    float* qk2o = out + 1048576 + 4194304;

    unsigned char* ws = (unsigned char*)d_ws;
    unsigned short* CAT24 = (unsigned short*)(ws + 0);          // [24][256][512] bf16 (h|sa|ca)
    unsigned short* hTb   = CAT24;
    unsigned short* saTb  = CAT24 + 8 * (size_t)kFW;
    unsigned short* caTb  = CAT24 + 16 * (size_t)kFW;
    unsigned short* SRCT  = (unsigned short*)(ws + 6291456);    // [8][256][512]
    unsigned short* QT    = (unsigned short*)(ws + 8388608);
    unsigned short* KT    = (unsigned short*)(ws + 10485760);
    unsigned short* PRE   = (unsigned short*)(ws + 12582912);   // up to 16 ch T
    unsigned short* Q2M   = (unsigned short*)(ws + 16777216);
    unsigned short* VPRE  = (unsigned short*)(ws + 18874368);   // N layout
    unsigned short* VN    = (unsigned short*)(ws + 20971520);
    unsigned short* ATTT  = (unsigned short*)(ws + 23068672);
    unsigned short* PB    = (unsigned short*)(ws + 25165824);   // [64][256][256]
    unsigned short* Z0T   = (unsigned short*)(ws + 33554432);   // [24][256][2048]
    unsigned short* Z0G   = (unsigned short*)(ws + 58720256);
    float*          Z2    = (float*)(ws + 83886080);            // [24][512][256] f32

    const float qscale = 0.044194173824159216f;   // 1/sqrt(512)
    dim3 blk(256);

    ln_t_kernel<<<32, blk, 0, stream>>>(x, ln_g, ln_b, hTb);
    tcvt_kernel<<<dim3(8, 8, 4), blk, 0, stream>>>(src, SRCT);

    // ---- self attention ----
    gemm_mfma<true, 2, 128><<<dim3(16, 8), blk, 0, stream>>>(sa_q_pw, hTb, PRE, 512, 256, 512,
        262144, 0, kFW, 0, kFW, 0, 0, 512, 512, 512, 1.0f);
    conv_t_kernel<<<512, blk, 0, stream>>>(PRE, sa_q_cw, sa_q_cb, QT);
    gemm_mfma<true, 2, 128><<<dim3(16, 8), blk, 0, stream>>>(sa_k_pw, hTb, PRE, 512, 256, 512,
        262144, 0, kFW, 0, kFW, 0, 0, 512, 512, 512, 1.0f);
    conv_t_kernel<<<512, blk, 0, stream>>>(PRE, sa_k_cw, sa_k_cb, KT);
    gemm_mfma<true, 1, 128><<<dim3(16, 8), blk, 0, stream>>>(sa_v_pw, hTb, VPRE, 512, 256, 512,
        262144, 0, kFW, 0, kFW, 0, 0, 512, 512, 256, 1.0f);
    conv_n_kernel<<<512, blk, 0, stream>>>(VPRE, sa_v_cw, sa_v_cb, VN);

    gemm_mfma<false, 0, 256><<<dim3(4, 64), blk, 0, stream>>>(QT, KT, qk1o, 256, 256, 64,
        kFW, 64, kFW, 64, 524288, 65536, 3, 512, 512, 256, qscale);
    softmax_kernel<<<16384, blk, 0, stream>>>(qk1o, PB);
    gemm_mfma<false, 1, 64><<<dim3(4, 64), blk, 0, stream>>>(PB, VN, ATTT, 256, 64, 256,
        524288, 65536, kFW, 16384, kFW, 64, 3, 256, 256, 512, 1.0f);

    gemm_mfma<true, 2, 128><<<dim3(16, 8), blk, 0, stream>>>(sa_o_pw, ATTT, saTb, 512, 256, 512,
        262144, 0, kFW, 0, kFW, 0, 0, 512, 512, 512, 1.0f);

    // ---- cross attention ----
    gemm_mfma<true, 2, 128><<<dim3(16, 16), blk, 0, stream>>>(ca_q_pw, CAT24, PRE, 512, 256, 512,
        262144, 0, kFW, 0, kFW, 0, 0, 512, 512, 512, 1.0f);
    mix16to8_t_kernel<<<512, blk, 0, stream>>>(PRE, ca_q_dw, Q2M);
    conv_t_kernel<<<512, blk, 0, stream>>>(Q2M, ca_q_cw, ca_q_cb, QT);
    gemm_mfma<true, 2, 128><<<dim3(16, 8), blk, 0, stream>>>(ca_k_pw, SRCT, PRE, 512, 256, 512,
        262144, 0, kFW, 0, kFW, 0, 0, 512, 512, 512, 1.0f);
    conv_t_kernel<<<512, blk, 0, stream>>>(PRE, ca_k_cw, ca_k_cb, KT);
    gemm_mfma<true, 1, 128><<<dim3(16, 8), blk, 0, stream>>>(ca_v_pw, SRCT, VPRE, 512, 256, 512,
        262144, 0, kFW, 0, kFW, 0, 0, 512, 512, 256, 1.0f);
    conv_n_kernel<<<512, blk, 0, stream>>>(VPRE, ca_v_cw, ca_v_cb, VN);

    gemm_mfma<false, 0, 256><<<dim3(4, 64), blk, 0, stream>>>(QT, KT, qk2o, 256, 256, 64,
        kFW, 64, kFW, 64, 524288, 65536, 3, 512, 512, 256, qscale);
    softmax_kernel<<<16384, blk, 0, stream>>>(qk2o, PB);
    gemm_mfma<false, 1, 64><<<dim3(4, 64), blk, 0, stream>>>(PB, VN, ATTT, 256, 64, 256,
        524288, 65536, kFW, 16384, kFW, 64, 3, 256, 256, 512, 1.0f);

    gemm_mfma<true, 2, 128><<<dim3(16, 8), blk, 0, stream>>>(ca_o_pw, ATTT, caTb, 512, 256, 512,
        262144, 0, kFW, 0, kFW, 0, 0, 512, 512, 512, 1.0f);

    // ---- FFN ----
    gemm_mfma<true, 2, 256><<<dim3(32, 24), blk, 0, stream>>>(ffn1_pw, CAT24, Z0T, 2048, 256, 512,
        1048576, 0, kFW, 0, 524288, 0, 0, 512, 512, 2048, 1.0f);
    gelu24_kernel<<<2048, blk, 0, stream>>>(Z0T, ffn1_dw, Z0G);
    gemm_mfma<true, 0, 256><<<dim3(8, 24), blk, 0, stream>>>(ffn2_pw, Z0G, Z2, 512, 256, 2048,
        1048576, 0, 524288, 0, kFW, 0, 0, 2048, 2048, 256, 1.0f);
    final_mix_add<<<512, blk, 0, stream>>>(x, Z2, ffn2_dw, out);
}

// Round 3
// 370.471 us; speedup vs baseline: 3.5563x; 1.3268x over previous
//
#include <hip/hip_runtime.h>
#include <math.h>

typedef __attribute__((ext_vector_type(4))) float f32x4;
typedef __attribute__((ext_vector_type(8))) short s16x8;
typedef __attribute__((ext_vector_type(4))) short s16x4;

__device__ __forceinline__ unsigned short f2b(float f) {
    union { float f; unsigned u; } v; v.f = f;
    unsigned r = v.u + 0x7fffu + ((v.u >> 16) & 1u);
    return (unsigned short)(r >> 16);
}
__device__ __forceinline__ float b2f(unsigned short u) {
    union { unsigned u; float f; } v; v.u = ((unsigned)u) << 16;
    return v.f;
}

constexpr int kF = 512;
constexpr int kW = 256;
constexpr int kFW = kF * kW;   // 131072

// ================= LayerNorm over f, output transposed bf16 [c][w][f] ==========
__global__ __launch_bounds__(256) void ln_t_kernel(const float* __restrict__ x,
                                                   const float* __restrict__ g,
                                                   const float* __restrict__ b,
                                                   unsigned short* __restrict__ hTb) {
    int c = blockIdx.x >> 4;
    int w0 = (blockIdx.x & 15) * 16;
    int t = threadIdx.x;
    int wi = t & 15, fg = t >> 4;          // fg 0..15, f-range fg*32..+31
    const float* xb = x + (size_t)c * kFW + w0 + wi;
    float sum = 0.f, sum2 = 0.f;
    for (int j = 0; j < 32; ++j) {
        float v = xb[(size_t)(fg * 32 + j) * kW];
        sum += v; sum2 += v * v;
    }
    __shared__ float s1[16][16], s2[16][16];
    s1[fg][wi] = sum; s2[fg][wi] = sum2;
    __syncthreads();
    float ts = 0.f, tq = 0.f;
    #pragma unroll
    for (int j = 0; j < 16; ++j) { ts += s1[j][wi]; tq += s2[j][wi]; }
    float mu = ts * (1.0f / 512.0f);
    float rstd = rsqrtf(tq * (1.0f / 512.0f) - mu * mu + 1e-5f);
    const float* gc = g + c * kF + fg * 32;
    const float* bc = b + c * kF + fg * 32;
    unsigned short* ob = hTb + (size_t)c * kFW + (size_t)(w0 + wi) * kF + fg * 32;
    for (int j = 0; j < 32; j += 4) {
        float v0 = xb[(size_t)(fg * 32 + j + 0) * kW];
        float v1 = xb[(size_t)(fg * 32 + j + 1) * kW];
        float v2 = xb[(size_t)(fg * 32 + j + 2) * kW];
        float v3 = xb[(size_t)(fg * 32 + j + 3) * kW];
        s16x4 p = { (short)f2b((v0 - mu) * rstd * gc[j + 0] + bc[j + 0]),
                    (short)f2b((v1 - mu) * rstd * gc[j + 1] + bc[j + 1]),
                    (short)f2b((v2 - mu) * rstd * gc[j + 2] + bc[j + 2]),
                    (short)f2b((v3 - mu) * rstd * gc[j + 3] + bc[j + 3]) };
        *(s16x4*)(&ob[j]) = p;
    }
}

// ================= transpose + cvt: [c][f][w] f32 -> [c][w][f] bf16 ============
__global__ __launch_bounds__(256) void tcvt_kernel(const float* __restrict__ in,
                                                   unsigned short* __restrict__ out) {
    int c = blockIdx.x, f0 = blockIdx.y * 64, w0 = blockIdx.z * 64;
    __shared__ float tile[64][65];
    int t = threadIdx.x;
    int tw = t & 63, tf4 = t >> 6;
    for (int i = 0; i < 16; ++i) {
        int f = tf4 * 16 + i;
        tile[f][tw] = in[(size_t)c * kFW + (size_t)(f0 + f) * kW + w0 + tw];
    }
    __syncthreads();
    int w = t >> 2, fc = (t & 3) * 16;
    unsigned short* ob = out + (size_t)c * kFW + (size_t)(w0 + w) * kF + f0 + fc;
    for (int j = 0; j < 16; j += 4) {
        s16x4 p = { (short)f2b(tile[fc + j + 0][w]), (short)f2b(tile[fc + j + 1][w]),
                    (short)f2b(tile[fc + j + 2][w]), (short)f2b(tile[fc + j + 3][w]) };
        *(s16x4*)(&ob[j]) = p;
    }
}

// ================= unified MFMA GEMM (with optional K-split via blockIdx.z) ====
template<bool AF32, int OMODE, int BN>
__global__ __launch_bounds__(256) void gemm_mfma(
    const void* __restrict__ Av, const unsigned short* __restrict__ B,
    void* __restrict__ Cv,
    int M, int N, int K,
    long a_hi, long a_lo, long b_hi, long b_lo, long c_hi, long c_lo,
    int bshift, int a_rs, int b_rs, int c_rs, float scale, long c_split)
{
    constexpr int NF = BN / 64;
    constexpr int WN = BN / 4;
    __shared__ unsigned char lds[8192 + BN * 128];

    int t = threadIdx.x;
    int lane = t & 63, wv = t >> 6;
    int l16 = lane & 15, l4 = lane >> 4;
    int swz = (lane & 7) << 4;

    int by = blockIdx.y;
    int bhi = by >> bshift, blo = by & ((1 << bshift) - 1);
    int ntiles = N / BN;
    int bm = (blockIdx.x / ntiles) * 64;
    int bn = (blockIdx.x % ntiles) * BN;
    int kof = blockIdx.z * K;

    const unsigned short* Bp = B + (size_t)bhi * b_hi + (size_t)blo * b_lo + (size_t)bn * b_rs;

    f32x4 acc[4][NF];
    #pragma unroll
    for (int i = 0; i < 4; ++i)
        #pragma unroll
        for (int j = 0; j < NF; ++j) acc[i][j] = (f32x4){0.f, 0.f, 0.f, 0.f};

    for (int k0 = 0; k0 < K; k0 += 64) {
        if constexpr (AF32) {
            const float* A = (const float*)Av + (size_t)bhi * a_hi + (size_t)blo * a_lo;
            #pragma unroll
            for (int it = 0; it < 4; ++it) {
                int idx = it * 256 + t;
                int r = idx >> 4, c4 = idx & 15;
                f32x4 v = *(const f32x4*)(A + (size_t)(bm + r) * a_rs + kof + k0 + c4 * 4);
                s16x4 pk = { (short)f2b(v.x), (short)f2b(v.y), (short)f2b(v.z), (short)f2b(v.w) };
                int off = r * 128 + ((c4 * 8) ^ ((r & 7) << 4));
                *(s16x4*)(&lds[off]) = pk;
            }
        } else {
            const unsigned short* A = (const unsigned short*)Av + (size_t)bhi * a_hi + (size_t)blo * a_lo;
            #pragma unroll
            for (int it = 0; it < 2; ++it) {
                int idx = it * 256 + t;
                int r = idx >> 3, ck = idx & 7;
                s16x8 v = *(const s16x8*)(A + (size_t)(bm + r) * a_rs + kof + k0 + ck * 8);
                int off = r * 128 + ((ck * 16) ^ ((r & 7) << 4));
                *(s16x8*)(&lds[off]) = v;
            }
        }
        #pragma unroll
        for (int it = 0; it < BN / 32; ++it) {
            int idx = it * 256 + t;
            int r = idx >> 3, ck = idx & 7;
            s16x8 v = *(const s16x8*)(Bp + (size_t)r * b_rs + kof + k0 + ck * 8);
            int off = 8192 + r * 128 + ((ck * 16) ^ ((r & 7) << 4));
            *(s16x8*)(&lds[off]) = v;
        }
        __syncthreads();
        #pragma unroll
        for (int ks = 0; ks < 2; ++ks) {
            s16x8 af[4], bfr[NF];
            #pragma unroll
            for (int mi = 0; mi < 4; ++mi)
                af[mi] = *(const s16x8*)(&lds[(mi * 16 + l16) * 128 + ((ks * 64 + l4 * 16) ^ swz)]);
            #pragma unroll
            for (int ni = 0; ni < NF; ++ni)
                bfr[ni] = *(const s16x8*)(&lds[8192 + (wv * WN + ni * 16 + l16) * 128 + ((ks * 64 + l4 * 16) ^ swz)]);
            #pragma unroll
            for (int mi = 0; mi < 4; ++mi)
                #pragma unroll
                for (int ni = 0; ni < NF; ++ni)
                    acc[mi][ni] = __builtin_amdgcn_mfma_f32_16x16x32_bf16(af[mi], bfr[ni], acc[mi][ni], 0, 0, 0);
        }
        __syncthreads();
    }

    if constexpr (OMODE == 0) {
        float* C = (float*)Cv + (size_t)bhi * c_hi + (size_t)blo * c_lo + (size_t)blockIdx.z * c_split;
        #pragma unroll
        for (int mi = 0; mi < 4; ++mi)
            #pragma unroll
            for (int ni = 0; ni < NF; ++ni) {
                int n = bn + wv * WN + ni * 16 + l16;
                int m0 = bm + mi * 16 + l4 * 4;
                #pragma unroll
                for (int r = 0; r < 4; ++r)
                    C[(size_t)(m0 + r) * c_rs + n] = acc[mi][ni][r] * scale;
            }
    } else if constexpr (OMODE == 1) {
        unsigned short* C = (unsigned short*)Cv + (size_t)bhi * c_hi + (size_t)blo * c_lo;
        #pragma unroll
        for (int mi = 0; mi < 4; ++mi)
            #pragma unroll
            for (int ni = 0; ni < NF; ++ni) {
                int n = bn + wv * WN + ni * 16 + l16;
                int m0 = bm + mi * 16 + l4 * 4;
                #pragma unroll
                for (int r = 0; r < 4; ++r)
                    C[(size_t)(m0 + r) * c_rs + n] = f2b(acc[mi][ni][r] * scale);
            }
    } else {
        unsigned short* C = (unsigned short*)Cv + (size_t)bhi * c_hi + (size_t)blo * c_lo;
        #pragma unroll
        for (int mi = 0; mi < 4; ++mi)
            #pragma unroll
            for (int ni = 0; ni < NF; ++ni) {
                int n = bn + wv * WN + ni * 16 + l16;
                int m0 = bm + mi * 16 + l4 * 4;
                s16x4 pk = { (short)f2b(acc[mi][ni][0] * scale), (short)f2b(acc[mi][ni][1] * scale),
                             (short)f2b(acc[mi][ni][2] * scale), (short)f2b(acc[mi][ni][3] * scale) };
                *(s16x4*)(&C[(size_t)n * c_rs + m0]) = pk;
            }
    }
}

// ================= batched 5-set projection GEMM (M=512,N=256,K=512,BN=64) =====
struct ProjArgs {
    const float* A[5];
    const unsigned short* B[5];
    unsigned short* C[5];
    int omode[5];      // 2 = T bf16 out, 1 = N bf16 out
};

__global__ __launch_bounds__(256) void proj_gemm(ProjArgs p, int K) {
    __shared__ unsigned char lds[16384];
    int t = threadIdx.x, lane = t & 63, wv = t >> 6;
    int l16 = lane & 15, l4 = lane >> 4;
    int swz = (lane & 7) << 4;
    int bx = blockIdx.x;
    int bm = (bx >> 2) * 64, bn = (bx & 3) * 64;
    int z = blockIdx.y, ws = z >> 3, c = z & 7;
    const float* A = p.A[ws] + (size_t)c * 262144;
    const unsigned short* B = p.B[ws] + (size_t)c * kFW + (size_t)bn * 512;
    f32x4 acc[4];
    #pragma unroll
    for (int i = 0; i < 4; ++i) acc[i] = (f32x4){0.f, 0.f, 0.f, 0.f};
    for (int k0 = 0; k0 < K; k0 += 64) {
        #pragma unroll
        for (int it = 0; it < 4; ++it) {
            int idx = it * 256 + t;
            int r = idx >> 4, c4 = idx & 15;
            f32x4 v = *(const f32x4*)(A + (size_t)(bm + r) * 512 + k0 + c4 * 4);
            s16x4 pk = { (short)f2b(v.x), (short)f2b(v.y), (short)f2b(v.z), (short)f2b(v.w) };
            *(s16x4*)(&lds[r * 128 + ((c4 * 8) ^ ((r & 7) << 4))]) = pk;
        }
        #pragma unroll
        for (int it = 0; it < 2; ++it) {
            int idx = it * 256 + t;
            int r = idx >> 3, ck = idx & 7;
            s16x8 v = *(const s16x8*)(B + (size_t)r * 512 + k0 + ck * 8);
            *(s16x8*)(&lds[8192 + r * 128 + ((ck * 16) ^ ((r & 7) << 4))]) = v;
        }
        __syncthreads();
        #pragma unroll
        for (int ks = 0; ks < 2; ++ks) {
            s16x8 bf = *(const s16x8*)(&lds[8192 + (wv * 16 + l16) * 128 + ((ks * 64 + l4 * 16) ^ swz)]);
            #pragma unroll
            for (int mi = 0; mi < 4; ++mi) {
                s16x8 af = *(const s16x8*)(&lds[(mi * 16 + l16) * 128 + ((ks * 64 + l4 * 16) ^ swz)]);
                acc[mi] = __builtin_amdgcn_mfma_f32_16x16x32_bf16(af, bf, acc[mi], 0, 0, 0);
            }
        }
        __syncthreads();
    }
    int n = bn + wv * 16 + l16;
    unsigned short* C = p.C[ws] + (size_t)c * kFW;
    if (p.omode[ws] == 2) {
        #pragma unroll
        for (int mi = 0; mi < 4; ++mi) {
            s16x4 pk = { (short)f2b(acc[mi][0]), (short)f2b(acc[mi][1]),
                         (short)f2b(acc[mi][2]), (short)f2b(acc[mi][3]) };
            *(s16x4*)(&C[(size_t)n * 512 + bm + mi * 16 + l4 * 4]) = pk;
        }
    } else {
        #pragma unroll
        for (int mi = 0; mi < 4; ++mi)
            #pragma unroll
            for (int r = 0; r < 4; ++r)
                C[(size_t)(bm + mi * 16 + l4 * 4 + r) * 256 + n] = f2b(acc[mi][r]);
    }
}

// ================= batched conv (1,3) + 8->8 mix, 5 groups =====================
struct ConvArgs {
    const unsigned short* in[5];
    unsigned short* out[5];
    const float* cw[5];
    const float* cb[5];
    int mode[5];   // 0 = T layout [c][w][f], 1 = N layout [c][f][w]
};

__global__ __launch_bounds__(256) void conv5_kernel(ConvArgs a) {
    int g = blockIdx.y;
    __shared__ float scw[192]; __shared__ float scb[8];
    int t = threadIdx.x;
    if (t < 192) scw[t] = a.cw[g][t];
    if (t >= 192 && t < 200) scb[t - 192] = a.cb[g][t - 192];
    __syncthreads();
    const unsigned short* in = a.in[g];
    unsigned short* out = a.out[g];
    int gi = blockIdx.x * 256 + t;
    int mode = a.mode[g];
    int w = mode ? (gi & 255) : (gi >> 9);
    int str = mode ? 1 : 512;
    float acc[8];
    #pragma unroll
    for (int o = 0; o < 8; ++o) acc[o] = scb[o];
    bool hm = w > 0, hp = w < 255;
    #pragma unroll
    for (int i = 0; i < 8; ++i) {
        size_t base = (size_t)i * kFW + gi;
        float xm = hm ? b2f(in[base - str]) : 0.f;
        float x0 = b2f(in[base]);
        float xp = hp ? b2f(in[base + str]) : 0.f;
        #pragma unroll
        for (int o = 0; o < 8; ++o) {
            const float* wp = &scw[(o * 8 + i) * 3];
            acc[o] += wp[0] * xm + wp[1] * x0 + wp[2] * xp;
        }
    }
    #pragma unroll
    for (int o = 0; o < 8; ++o) out[(size_t)o * kFW + gi] = f2b(acc[o]);
}

// ================= fused 16->8 mix + conv (CA query path), T layout ===========
__global__ __launch_bounds__(256) void mixconv_kernel(const unsigned short* __restrict__ in,
                                                      const float* __restrict__ dw,
                                                      const float* __restrict__ cw,
                                                      const float* __restrict__ cb,
                                                      unsigned short* __restrict__ out) {
    __shared__ float sdw[128], scw[192], scb[8];
    int t = threadIdx.x;
    if (t < 128) sdw[t] = dw[t];
    if (t >= 128 && t < 136) scb[t - 128] = cb[t - 128];
    if (t < 192) scw[t] = cw[t];
    __syncthreads();
    int gi = blockIdx.x * 256 + t;
    int w = gi >> 9;
    bool hm = w > 0, hp = w < 255;
    float xc[16], xm[16], xp[16];
    #pragma unroll
    for (int cc = 0; cc < 16; ++cc) {
        size_t base = (size_t)cc * kFW + gi;
        xc[cc] = b2f(in[base]);
        xm[cc] = hm ? b2f(in[base - 512]) : 0.f;
        xp[cc] = hp ? b2f(in[base + 512]) : 0.f;
    }
    float mm[8], m0[8], mp[8];
    #pragma unroll
    for (int o = 0; o < 8; ++o) {
        float am = 0.f, a0 = 0.f, ap = 0.f;
        #pragma unroll
        for (int cc = 0; cc < 16; ++cc) {
            float wv = sdw[o * 16 + cc];
            am += wv * xm[cc]; a0 += wv * xc[cc]; ap += wv * xp[cc];
        }
        mm[o] = am; m0[o] = a0; mp[o] = ap;
    }
    #pragma unroll
    for (int o = 0; o < 8; ++o) {
        float acc = scb[o];
        #pragma unroll
        for (int i = 0; i < 8; ++i) {
            const float* wp = &scw[(o * 8 + i) * 3];
            acc += wp[0] * mm[i] + wp[1] * m0[i] + wp[2] * mp[i];
        }
        out[(size_t)o * kFW + gi] = f2b(acc);
    }
}

// ================= fused QK^T + scale + softmax ===============================
// grid (4 m-tiles, 64 ch). Writes S (f32, required output) and P (bf16).
__global__ __launch_bounds__(256) void qk_softmax_kernel(
    const unsigned short* __restrict__ Qt, const unsigned short* __restrict__ Kt,
    float* __restrict__ S, unsigned short* __restrict__ P, float scale)
{
    __shared__ unsigned char lds[40960];
    __shared__ float smax[4][64];
    __shared__ float ssum[4][64];
    int t = threadIdx.x, lane = t & 63, wv = t >> 6;
    int l16 = lane & 15, l4 = lane >> 4;
    int swz = (lane & 7) << 4;
    int ch = blockIdx.y, c = ch >> 3, h = ch & 7;
    int bm = blockIdx.x * 64;
    const unsigned short* Qb = Qt + (size_t)c * kFW + h * 64;
    const unsigned short* Kb = Kt + (size_t)c * kFW + h * 64;
    float* Sb = S + (size_t)ch * 65536;
    unsigned short* Pb = P + (size_t)ch * 65536;

    #pragma unroll
    for (int it = 0; it < 2; ++it) {
        int idx = it * 256 + t; int r = idx >> 3, ck = idx & 7;
        s16x8 v = *(const s16x8*)(Qb + (size_t)(bm + r) * 512 + ck * 8);
        *(s16x8*)(&lds[r * 128 + ((ck * 16) ^ ((r & 7) << 4))]) = v;
    }
    #pragma unroll
    for (int it = 0; it < 8; ++it) {
        int idx = it * 256 + t; int r = idx >> 3, ck = idx & 7;
        s16x8 v = *(const s16x8*)(Kb + (size_t)r * 512 + ck * 8);
        *(s16x8*)(&lds[8192 + r * 128 + ((ck * 16) ^ ((r & 7) << 4))]) = v;
    }
    __syncthreads();
    f32x4 acc[4][4];
    #pragma unroll
    for (int i = 0; i < 4; ++i)
        #pragma unroll
        for (int j = 0; j < 4; ++j) acc[i][j] = (f32x4){0.f, 0.f, 0.f, 0.f};
    #pragma unroll
    for (int ks = 0; ks < 2; ++ks) {
        s16x8 af[4], bfr[4];
        #pragma unroll
        for (int mi = 0; mi < 4; ++mi)
            af[mi] = *(const s16x8*)(&lds[(mi * 16 + l16) * 128 + ((ks * 64 + l4 * 16) ^ swz)]);
        #pragma unroll
        for (int ni = 0; ni < 4; ++ni)
            bfr[ni] = *(const s16x8*)(&lds[8192 + (wv * 64 + ni * 16 + l16) * 128 + ((ks * 64 + l4 * 16) ^ swz)]);
        #pragma unroll
        for (int mi = 0; mi < 4; ++mi)
            #pragma unroll
            for (int ni = 0; ni < 4; ++ni)
                acc[mi][ni] = __builtin_amdgcn_mfma_f32_16x16x32_bf16(af[mi], bfr[ni], acc[mi][ni], 0, 0, 0);
    }
    // scale + write S
    #pragma unroll
    for (int mi = 0; mi < 4; ++mi)
        #pragma unroll
        for (int ni = 0; ni < 4; ++ni) {
            acc[mi][ni] *= scale;
            int col = wv * 64 + ni * 16 + l16;
            int row0 = bm + mi * 16 + l4 * 4;
            #pragma unroll
            for (int r = 0; r < 4; ++r)
                Sb[(size_t)(row0 + r) * 256 + col] = acc[mi][ni][r];
        }
    // row max (per-lane over ni, then across 16 lanes, then across 4 waves)
    float rmax[4][4];
    #pragma unroll
    for (int mi = 0; mi < 4; ++mi)
        #pragma unroll
        for (int r = 0; r < 4; ++r)
            rmax[mi][r] = fmaxf(fmaxf(acc[mi][0][r], acc[mi][1][r]), fmaxf(acc[mi][2][r], acc[mi][3][r]));
    #pragma unroll
    for (int d = 1; d < 16; d <<= 1)
        #pragma unroll
        for (int mi = 0; mi < 4; ++mi)
            #pragma unroll
            for (int r = 0; r < 4; ++r)
                rmax[mi][r] = fmaxf(rmax[mi][r], __shfl_xor(rmax[mi][r], d));
    if (l16 == 0)
        #pragma unroll
        for (int mi = 0; mi < 4; ++mi)
            #pragma unroll
            for (int r = 0; r < 4; ++r)
                smax[wv][mi * 16 + l4 * 4 + r] = rmax[mi][r];
    __syncthreads();
    float rM[4][4], rsum[4][4];
    #pragma unroll
    for (int mi = 0; mi < 4; ++mi)
        #pragma unroll
        for (int r = 0; r < 4; ++r) {
            int row = mi * 16 + l4 * 4 + r;
            rM[mi][r] = fmaxf(fmaxf(smax[0][row], smax[1][row]), fmaxf(smax[2][row], smax[3][row]));
            rsum[mi][r] = 0.f;
        }
    #pragma unroll
    for (int mi = 0; mi < 4; ++mi)
        #pragma unroll
        for (int ni = 0; ni < 4; ++ni)
            #pragma unroll
            for (int r = 0; r < 4; ++r) {
                float e = __expf(acc[mi][ni][r] - rM[mi][r]);
                acc[mi][ni][r] = e;
                rsum[mi][r] += e;
            }
    #pragma unroll
    for (int d = 1; d < 16; d <<= 1)
        #pragma unroll
        for (int mi = 0; mi < 4; ++mi)
            #pragma unroll
            for (int r = 0; r < 4; ++r)
                rsum[mi][r] += __shfl_xor(rsum[mi][r], d);
    if (l16 == 0)
        #pragma unroll
        for (int mi = 0; mi < 4; ++mi)
            #pragma unroll
            for (int r = 0; r < 4; ++r)
                ssum[wv][mi * 16 + l4 * 4 + r] = rsum[mi][r];
    __syncthreads();
    #pragma unroll
    for (int mi = 0; mi < 4; ++mi)
        #pragma unroll
        for (int r = 0; r < 4; ++r) {
            int row = mi * 16 + l4 * 4 + r;
            float inv = 1.f / (ssum[0][row] + ssum[1][row] + ssum[2][row] + ssum[3][row]);
            #pragma unroll
            for (int ni = 0; ni < 4; ++ni)
                Pb[(size_t)(bm + row) * 256 + wv * 64 + ni * 16 + l16] = f2b(acc[mi][ni][r] * inv);
        }
}

// ================= FFN1: 24->24 mix + exact GELU, in place ====================
__global__ __launch_bounds__(256) void gelu24_kernel(unsigned short* __restrict__ z,
                                                     const float* __restrict__ dw) {
    __shared__ float sdw[576];
    int t = threadIdx.x;
    for (int i = t; i < 576; i += 256) sdw[i] = dw[i];
    __syncthreads();
    size_t gi = (size_t)blockIdx.x * 256 + t;
    const size_t CH = (size_t)256 * 2048;
    float xv[24];
    #pragma unroll
    for (int cc = 0; cc < 24; ++cc) xv[cc] = b2f(z[cc * CH + gi]);
    #pragma unroll
    for (int o = 0; o < 24; ++o) {
        float s = 0.f;
        #pragma unroll
        for (int cc = 0; cc < 24; ++cc) s += sdw[o * 24 + cc] * xv[cc];
        s = 0.5f * s * (1.0f + erff(s * 0.7071067811865475f));
        z[o * CH + gi] = f2b(s);
    }
}

// ================= FFN2 reduce(4 partials) + 24->8 mix + residual =============
__global__ __launch_bounds__(256) void final_mix_add4(const float* __restrict__ x,
                                                      const float* __restrict__ z2,
                                                      const float* __restrict__ dw,
                                                      float* __restrict__ out) {
    __shared__ float sdw[192];
    int t = threadIdx.x;
    if (t < 192) sdw[t] = dw[t];
    __syncthreads();
    int gi = blockIdx.x * 256 + t;
    const size_t PSZ = (size_t)24 * kFW;
    float xv[24];
    #pragma unroll
    for (int cc = 0; cc < 24; ++cc) {
        size_t o = (size_t)cc * kFW + gi;
        xv[cc] = z2[o] + z2[PSZ + o] + z2[2 * PSZ + o] + z2[3 * PSZ + o];
    }
    #pragma unroll
    for (int o = 0; o < 8; ++o) {
        float s = 0.f;
        #pragma unroll
        for (int cc = 0; cc < 24; ++cc) s += sdw[o * 24 + cc] * xv[cc];
        out[(size_t)o * kFW + gi] = x[(size_t)o * kFW + gi] + s;
    }
}

// ================= launch =====================================================
extern "C" void kernel_launch(void* const* d_in, const int* in_sizes, int n_in,
                              void* d_out, int out_size, void* d_ws, size_t ws_size,
                              hipStream_t stream) {
    const float* x       = (const float*)d_in[0];
    const float* src     = (const float*)d_in[1];
    const float* ln_g    = (const float*)d_in[2];
    const float* ln_b    = (const float*)d_in[3];
    const float* sa_q_pw = (const float*)d_in[4];
    const float* sa_q_cw = (const float*)d_in[5];
    const float* sa_q_cb = (const float*)d_in[6];
    const float* sa_k_pw = (const float*)d_in[7];
    const float* sa_k_cw = (const float*)d_in[8];
    const float* sa_k_cb = (const float*)d_in[9];
    const float* sa_v_pw = (const float*)d_in[10];
    const float* sa_v_cw = (const float*)d_in[11];
    const float* sa_v_cb = (const float*)d_in[12];
    const float* sa_o_pw = (const float*)d_in[13];
    const float* ca_q_pw = (const float*)d_in[14];
    const float* ca_q_dw = (const float*)d_in[15];
    const float* ca_q_cw = (const float*)d_in[16];
    const float* ca_q_cb = (const float*)d_in[17];
    const float* ca_k_pw = (const float*)d_in[18];
    const float* ca_k_cw = (const float*)d_in[19];
    const float* ca_k_cb = (const float*)d_in[20];
    const float* ca_v_pw = (const float*)d_in[21];
    const float* ca_v_cw = (const float*)d_in[22];
    const float* ca_v_cb = (const float*)d_in[23];
    const float* ca_o_pw = (const float*)d_in[24];
    const float* ffn1_pw = (const float*)d_in[25];
    const float* ffn1_dw = (const float*)d_in[26];
    const float* ffn2_pw = (const float*)d_in[27];
    const float* ffn2_dw = (const float*)d_in[28];

    float* out  = (float*)d_out;
    float* qk1o = out + 1048576;
    float* qk2o = out + 1048576 + 4194304;

    unsigned char* ws = (unsigned char*)d_ws;
    unsigned short* CAT24  = (unsigned short*)(ws + 0);         // [24][256][512] (h|sa|ca)
    unsigned short* hTb    = CAT24;
    unsigned short* saTb   = CAT24 + 8 * (size_t)kFW;
    unsigned short* caTb   = CAT24 + 16 * (size_t)kFW;
    unsigned short* SRCT   = (unsigned short*)(ws + 6291456);
    unsigned short* preQ   = (unsigned short*)(ws + 8388608);
    unsigned short* preK   = (unsigned short*)(ws + 10485760);
    unsigned short* preVsa = (unsigned short*)(ws + 12582912);
    unsigned short* preKca = (unsigned short*)(ws + 14680064);
    unsigned short* preVca = (unsigned short*)(ws + 16777216);
    unsigned short* QT     = (unsigned short*)(ws + 18874368);
    unsigned short* KT     = (unsigned short*)(ws + 20971520);
    unsigned short* VNsa   = (unsigned short*)(ws + 23068672);
    unsigned short* KTca   = (unsigned short*)(ws + 25165824);
    unsigned short* VNca   = (unsigned short*)(ws + 27262976);
    unsigned short* PRE16  = (unsigned short*)(ws + 29360128);  // 4 MB
    unsigned short* QTca   = (unsigned short*)(ws + 33554432);
    unsigned short* ATTT   = (unsigned short*)(ws + 35651584);
    unsigned short* PB     = (unsigned short*)(ws + 37748736);  // 8 MB
    // FFN phase (attention scratch dead by then):
    unsigned short* Z0T    = (unsigned short*)(ws + 8388608);   // 24 MB [24][256][2048]
    float*          Z2P    = (float*)(ws + 33554432);           // 48 MB: 4 partials

    const float qscale = 0.044194173824159216f;   // 1/sqrt(512)
    dim3 blk(256);

    ln_t_kernel<<<128, blk, 0, stream>>>(x, ln_g, ln_b, hTb);
    tcvt_kernel<<<dim3(8, 8, 4), blk, 0, stream>>>(src, SRCT);

    // ---- batched projections: SA q,k,v + CA k,v ----
    ProjArgs p5;
    p5.A[0] = sa_q_pw; p5.B[0] = hTb;  p5.C[0] = preQ;   p5.omode[0] = 2;
    p5.A[1] = sa_k_pw; p5.B[1] = hTb;  p5.C[1] = preK;   p5.omode[1] = 2;
    p5.A[2] = sa_v_pw; p5.B[2] = hTb;  p5.C[2] = preVsa; p5.omode[2] = 1;
    p5.A[3] = ca_k_pw; p5.B[3] = SRCT; p5.C[3] = preKca; p5.omode[3] = 2;
    p5.A[4] = ca_v_pw; p5.B[4] = SRCT; p5.C[4] = preVca; p5.omode[4] = 1;
    proj_gemm<<<dim3(32, 40), blk, 0, stream>>>(p5, 512);

    ConvArgs c5;
    c5.in[0] = preQ;   c5.out[0] = QT;   c5.cw[0] = sa_q_cw; c5.cb[0] = sa_q_cb; c5.mode[0] = 0;
    c5.in[1] = preK;   c5.out[1] = KT;   c5.cw[1] = sa_k_cw; c5.cb[1] = sa_k_cb; c5.mode[1] = 0;
    c5.in[2] = preVsa; c5.out[2] = VNsa; c5.cw[2] = sa_v_cw; c5.cb[2] = sa_v_cb; c5.mode[2] = 1;
    c5.in[3] = preKca; c5.out[3] = KTca; c5.cw[3] = ca_k_cw; c5.cb[3] = ca_k_cb; c5.mode[3] = 0;
    c5.in[4] = preVca; c5.out[4] = VNca; c5.cw[4] = ca_v_cw; c5.cb[4] = ca_v_cb; c5.mode[4] = 1;
    conv5_kernel<<<dim3(512, 5), blk, 0, stream>>>(c5);

    // ---- self attention ----
    qk_softmax_kernel<<<dim3(4, 64), blk, 0, stream>>>(QT, KT, qk1o, PB, qscale);
    gemm_mfma<false, 1, 64><<<dim3(4, 64), blk, 0, stream>>>(PB, VNsa, ATTT, 256, 64, 256,
        524288, 65536, kFW, 16384, kFW, 64, 3, 256, 256, 512, 1.0f, 0);
    gemm_mfma<true, 2, 64><<<dim3(32, 8), blk, 0, stream>>>(sa_o_pw, ATTT, saTb, 512, 256, 512,
        262144, 0, kFW, 0, kFW, 0, 0, 512, 512, 512, 1.0f, 0);

    // ---- cross attention ----
    ProjArgs pq;
    pq.A[0] = ca_q_pw;                p5.B[0] = nullptr;
    pq.B[0] = CAT24;                  pq.C[0] = PRE16;               pq.omode[0] = 2;
    pq.A[1] = ca_q_pw + 8 * 262144;   pq.B[1] = CAT24 + 8 * (size_t)kFW;
    pq.C[1] = PRE16 + 8 * (size_t)kFW; pq.omode[1] = 2;
    pq.A[2] = pq.A[0]; pq.B[2] = pq.B[0]; pq.C[2] = pq.C[0]; pq.omode[2] = 2;
    pq.A[3] = pq.A[0]; pq.B[3] = pq.B[0]; pq.C[3] = pq.C[0]; pq.omode[3] = 2;
    pq.A[4] = pq.A[0]; pq.B[4] = pq.B[0]; pq.C[4] = pq.C[0]; pq.omode[4] = 2;
    proj_gemm<<<dim3(32, 16), blk, 0, stream>>>(pq, 512);
    mixconv_kernel<<<512, blk, 0, stream>>>(PRE16, ca_q_dw, ca_q_cw, ca_q_cb, QTca);

    qk_softmax_kernel<<<dim3(4, 64), blk, 0, stream>>>(QTca, KTca, qk2o, PB, qscale);
    gemm_mfma<false, 1, 64><<<dim3(4, 64), blk, 0, stream>>>(PB, VNca, ATTT, 256, 64, 256,
        524288, 65536, kFW, 16384, kFW, 64, 3, 256, 256, 512, 1.0f, 0);
    gemm_mfma<true, 2, 64><<<dim3(32, 8), blk, 0, stream>>>(ca_o_pw, ATTT, caTb, 512, 256, 512,
        262144, 0, kFW, 0, kFW, 0, 0, 512, 512, 512, 1.0f, 0);

    // ---- FFN ----
    gemm_mfma<true, 2, 128><<<dim3(64, 24), blk, 0, stream>>>(ffn1_pw, CAT24, Z0T, 2048, 256, 512,
        1048576, 0, kFW, 0, 524288, 0, 0, 512, 512, 2048, 1.0f, 0);
    gelu24_kernel<<<2048, blk, 0, stream>>>(Z0T, ffn1_dw);
    gemm_mfma<true, 0, 256><<<dim3(8, 24, 4), blk, 0, stream>>>(ffn2_pw, Z0T, Z2P, 512, 256, 512,
        1048576, 0, 524288, 0, kFW, 0, 0, 2048, 2048, 256, 1.0f, 3145728);
    final_mix_add4<<<512, blk, 0, stream>>>(x, Z2P, ffn2_dw, out);
}

// Round 4
// 333.282 us; speedup vs baseline: 3.9531x; 1.1116x over previous
//
#include <hip/hip_runtime.h>
#include <math.h>

typedef __attribute__((ext_vector_type(4))) float f32x4;
typedef __attribute__((ext_vector_type(8))) short s16x8;
typedef __attribute__((ext_vector_type(4))) short s16x4;

__device__ __forceinline__ unsigned short f2b(float f) {
    union { float f; unsigned u; } v; v.f = f;
    unsigned r = v.u + 0x7fffu + ((v.u >> 16) & 1u);
    return (unsigned short)(r >> 16);
}
__device__ __forceinline__ float b2f(unsigned short u) {
    union { unsigned u; float f; } v; v.u = ((unsigned)u) << 16;
    return v.f;
}

constexpr int kF = 512;
constexpr int kW = 256;
constexpr int kFW = kF * kW;   // 131072

// ================= LayerNorm over f, output transposed bf16 [c][w][f] ==========
__global__ __launch_bounds__(256) void ln_t_kernel(const float* __restrict__ x,
                                                   const float* __restrict__ g,
                                                   const float* __restrict__ b,
                                                   unsigned short* __restrict__ hTb) {
    int c = blockIdx.x >> 4;
    int w0 = (blockIdx.x & 15) * 16;
    int t = threadIdx.x;
    int wi = t & 15, fg = t >> 4;          // fg 0..15, f-range fg*32..+31
    const float* xb = x + (size_t)c * kFW + w0 + wi;
    float sum = 0.f, sum2 = 0.f;
    for (int j = 0; j < 32; ++j) {
        float v = xb[(size_t)(fg * 32 + j) * kW];
        sum += v; sum2 += v * v;
    }
    __shared__ float s1[16][16], s2[16][16];
    s1[fg][wi] = sum; s2[fg][wi] = sum2;
    __syncthreads();
    float ts = 0.f, tq = 0.f;
    #pragma unroll
    for (int j = 0; j < 16; ++j) { ts += s1[j][wi]; tq += s2[j][wi]; }
    float mu = ts * (1.0f / 512.0f);
    float rstd = rsqrtf(tq * (1.0f / 512.0f) - mu * mu + 1e-5f);
    const float* gc = g + c * kF + fg * 32;
    const float* bc = b + c * kF + fg * 32;
    unsigned short* ob = hTb + (size_t)c * kFW + (size_t)(w0 + wi) * kF + fg * 32;
    for (int j = 0; j < 32; j += 4) {
        float v0 = xb[(size_t)(fg * 32 + j + 0) * kW];
        float v1 = xb[(size_t)(fg * 32 + j + 1) * kW];
        float v2 = xb[(size_t)(fg * 32 + j + 2) * kW];
        float v3 = xb[(size_t)(fg * 32 + j + 3) * kW];
        s16x4 p = { (short)f2b((v0 - mu) * rstd * gc[j + 0] + bc[j + 0]),
                    (short)f2b((v1 - mu) * rstd * gc[j + 1] + bc[j + 1]),
                    (short)f2b((v2 - mu) * rstd * gc[j + 2] + bc[j + 2]),
                    (short)f2b((v3 - mu) * rstd * gc[j + 3] + bc[j + 3]) };
        *(s16x4*)(&ob[j]) = p;
    }
}

// ================= transpose + cvt: [c][f][w] f32 -> [c][w][f] bf16 ============
__global__ __launch_bounds__(256) void tcvt_kernel(const float* __restrict__ in,
                                                   unsigned short* __restrict__ out) {
    int c = blockIdx.x, f0 = blockIdx.y * 64, w0 = blockIdx.z * 64;
    __shared__ float tile[64][65];
    int t = threadIdx.x;
    int tw = t & 63, tf4 = t >> 6;
    for (int i = 0; i < 16; ++i) {
        int f = tf4 * 16 + i;
        tile[f][tw] = in[(size_t)c * kFW + (size_t)(f0 + f) * kW + w0 + tw];
    }
    __syncthreads();
    int w = t >> 2, fc = (t & 3) * 16;
    unsigned short* ob = out + (size_t)c * kFW + (size_t)(w0 + w) * kF + f0 + fc;
    for (int j = 0; j < 16; j += 4) {
        s16x4 p = { (short)f2b(tile[fc + j + 0][w]), (short)f2b(tile[fc + j + 1][w]),
                    (short)f2b(tile[fc + j + 2][w]), (short)f2b(tile[fc + j + 3][w]) };
        *(s16x4*)(&ob[j]) = p;
    }
}

// ================= weight-streaming GEMM ======================================
// Y[c][m][n] = sum_k W[c][m][k](f32) * Bt[c][n][k](bf16)
// A fragments stream straight from global (per-lane row, reg prefetch, no barrier
// in the k-loop). B chunk (64 n x 256 k bf16 = 32 KB) staged in LDS, XOR-swizzled.
// omode: 0 = f32 [m][n] (c row stride 256), 1 = bf16 [m][n], 2 = bf16 T [n][m] (row stride M)
struct WSeg { const float* A; const unsigned short* B; void* C; int omode; };
struct WB5 { WSeg s[5]; };

__global__ __launch_bounds__(256) void wgemm(WB5 wb, int M, int K,
                                             long a_ch, long b_ch, long c_ch,
                                             int segshift) {
    __shared__ unsigned short lds[16384];   // 64 rows x 256 shorts (512 B)
    int t = threadIdx.x, lane = t & 63, wv = t >> 6;
    int l16 = lane & 15, l4 = lane >> 4;
    int y = blockIdx.y;
    int seg = y >> segshift, c = y & ((1 << segshift) - 1);
    WSeg sg = wb.s[seg];
    int bm = (blockIdx.x >> 2) * 64;
    int bn = (blockIdx.x & 3) * 64;
    const float* A = sg.A + (size_t)c * a_ch;
    const unsigned short* B = sg.B + (size_t)c * b_ch + (size_t)bn * K;
    const float* arow = A + (size_t)(bm + wv * 16 + l16) * K + l4 * 8;

    f32x4 acc[4];
    #pragma unroll
    for (int i = 0; i < 4; ++i) acc[i] = (f32x4){0.f, 0.f, 0.f, 0.f};

    f32x4 pa0 = *(const f32x4*)(arow);
    f32x4 pa1 = *(const f32x4*)(arow + 4);

    for (int kc = 0; kc < K; kc += 256) {
        if (kc) __syncthreads();
        #pragma unroll
        for (int it = 0; it < 8; ++it) {
            int id = it * 256 + t;
            int r = id >> 5, ck = id & 31;
            s16x8 v = *(const s16x8*)(B + (size_t)r * K + kc + ck * 8);
            lds[r * 256 + ((ck * 8) ^ ((r & 7) << 3))] = 0;   // placeholder overwritten below
            *(s16x8*)(&lds[r * 256 + ((ck * 8) ^ ((r & 7) << 3))]) = v;
        }
        __syncthreads();
        #pragma unroll
        for (int ks = 0; ks < 8; ++ks) {
            f32x4 c0 = pa0, c1 = pa1;
            int nk = kc + (ks + 1) * 32;
            if (nk < K) {
                pa0 = *(const f32x4*)(arow + nk);
                pa1 = *(const f32x4*)(arow + nk + 4);
            }
            s16x8 af = { (short)f2b(c0.x), (short)f2b(c0.y), (short)f2b(c0.z), (short)f2b(c0.w),
                         (short)f2b(c1.x), (short)f2b(c1.y), (short)f2b(c1.z), (short)f2b(c1.w) };
            #pragma unroll
            for (int ni = 0; ni < 4; ++ni) {
                int rr = ni * 16 + l16;
                s16x8 bf = *(const s16x8*)(&lds[rr * 256 + ((ks * 32 + l4 * 8) ^ ((rr & 7) << 3))]);
                acc[ni] = __builtin_amdgcn_mfma_f32_16x16x32_bf16(af, bf, acc[ni], 0, 0, 0);
            }
        }
    }

    int m0 = bm + wv * 16 + l4 * 4;
    if (sg.omode == 2) {
        unsigned short* C = (unsigned short*)sg.C + (size_t)c * c_ch;
        #pragma unroll
        for (int ni = 0; ni < 4; ++ni) {
            int n = bn + ni * 16 + l16;
            s16x4 pk = { (short)f2b(acc[ni][0]), (short)f2b(acc[ni][1]),
                         (short)f2b(acc[ni][2]), (short)f2b(acc[ni][3]) };
            *(s16x4*)(&C[(size_t)n * M + m0]) = pk;
        }
    } else if (sg.omode == 1) {
        unsigned short* C = (unsigned short*)sg.C + (size_t)c * c_ch;
        #pragma unroll
        for (int ni = 0; ni < 4; ++ni) {
            int n = bn + ni * 16 + l16;
            #pragma unroll
            for (int r = 0; r < 4; ++r)
                C[(size_t)(m0 + r) * 256 + n] = f2b(acc[ni][r]);
        }
    } else {
        float* C = (float*)sg.C + (size_t)c * c_ch;
        #pragma unroll
        for (int ni = 0; ni < 4; ++ni) {
            int n = bn + ni * 16 + l16;
            #pragma unroll
            for (int r = 0; r < 4; ++r)
                C[(size_t)(m0 + r) * 256 + n] = acc[ni][r];
        }
    }
}

// ================= bf16-A MFMA GEMM (PV only) =================================
template<int OMODE, int BN>
__global__ __launch_bounds__(256) void gemm_mfma(
    const unsigned short* __restrict__ Av, const unsigned short* __restrict__ B,
    void* __restrict__ Cv,
    int M, int N, int K,
    long a_hi, long a_lo, long b_hi, long b_lo, long c_hi, long c_lo,
    int bshift, int a_rs, int b_rs, int c_rs, float scale)
{
    constexpr int NF = BN / 64;
    constexpr int WN = BN / 4;
    __shared__ unsigned char lds[8192 + BN * 128];

    int t = threadIdx.x;
    int lane = t & 63, wv = t >> 6;
    int l16 = lane & 15, l4 = lane >> 4;
    int swz = (lane & 7) << 4;

    int by = blockIdx.y;
    int bhi = by >> bshift, blo = by & ((1 << bshift) - 1);
    int ntiles = N / BN;
    int bm = (blockIdx.x / ntiles) * 64;
    int bn = (blockIdx.x % ntiles) * BN;

    const unsigned short* Bp = B + (size_t)bhi * b_hi + (size_t)blo * b_lo + (size_t)bn * b_rs;
    const unsigned short* A = Av + (size_t)bhi * a_hi + (size_t)blo * a_lo;

    f32x4 acc[4][NF];
    #pragma unroll
    for (int i = 0; i < 4; ++i)
        #pragma unroll
        for (int j = 0; j < NF; ++j) acc[i][j] = (f32x4){0.f, 0.f, 0.f, 0.f};

    for (int k0 = 0; k0 < K; k0 += 64) {
        #pragma unroll
        for (int it = 0; it < 2; ++it) {
            int idx = it * 256 + t;
            int r = idx >> 3, ck = idx & 7;
            s16x8 v = *(const s16x8*)(A + (size_t)(bm + r) * a_rs + k0 + ck * 8);
            int off = r * 128 + ((ck * 16) ^ ((r & 7) << 4));
            *(s16x8*)(&lds[off]) = v;
        }
        #pragma unroll
        for (int it = 0; it < BN / 32; ++it) {
            int idx = it * 256 + t;
            int r = idx >> 3, ck = idx & 7;
            s16x8 v = *(const s16x8*)(Bp + (size_t)r * b_rs + k0 + ck * 8);
            int off = 8192 + r * 128 + ((ck * 16) ^ ((r & 7) << 4));
            *(s16x8*)(&lds[off]) = v;
        }
        __syncthreads();
        #pragma unroll
        for (int ks = 0; ks < 2; ++ks) {
            s16x8 af[4], bfr[NF];
            #pragma unroll
            for (int mi = 0; mi < 4; ++mi)
                af[mi] = *(const s16x8*)(&lds[(mi * 16 + l16) * 128 + ((ks * 64 + l4 * 16) ^ swz)]);
            #pragma unroll
            for (int ni = 0; ni < NF; ++ni)
                bfr[ni] = *(const s16x8*)(&lds[8192 + (wv * WN + ni * 16 + l16) * 128 + ((ks * 64 + l4 * 16) ^ swz)]);
            #pragma unroll
            for (int mi = 0; mi < 4; ++mi)
                #pragma unroll
                for (int ni = 0; ni < NF; ++ni)
                    acc[mi][ni] = __builtin_amdgcn_mfma_f32_16x16x32_bf16(af[mi], bfr[ni], acc[mi][ni], 0, 0, 0);
        }
        __syncthreads();
    }

    unsigned short* C = (unsigned short*)Cv + (size_t)bhi * c_hi + (size_t)blo * c_lo;
    #pragma unroll
    for (int mi = 0; mi < 4; ++mi)
        #pragma unroll
        for (int ni = 0; ni < NF; ++ni) {
            int n = bn + wv * WN + ni * 16 + l16;
            int m0 = bm + mi * 16 + l4 * 4;
            #pragma unroll
            for (int r = 0; r < 4; ++r)
                C[(size_t)(m0 + r) * c_rs + n] = f2b(acc[mi][ni][r] * scale);
        }
}

// ================= batched conv (1,3) + 8->8 mix, 5 groups =====================
struct ConvArgs {
    const unsigned short* in[5];
    unsigned short* out[5];
    const float* cw[5];
    const float* cb[5];
    int mode[5];   // 0 = T layout [c][w][f], 1 = N layout [c][f][w]
};

__global__ __launch_bounds__(256) void conv5_kernel(ConvArgs a) {
    int g = blockIdx.y;
    __shared__ float scw[192]; __shared__ float scb[8];
    int t = threadIdx.x;
    if (t < 192) scw[t] = a.cw[g][t];
    if (t >= 192 && t < 200) scb[t - 192] = a.cb[g][t - 192];
    __syncthreads();
    const unsigned short* in = a.in[g];
    unsigned short* out = a.out[g];
    int gi = blockIdx.x * 256 + t;
    int mode = a.mode[g];
    int w = mode ? (gi & 255) : (gi >> 9);
    int str = mode ? 1 : 512;
    float acc[8];
    #pragma unroll
    for (int o = 0; o < 8; ++o) acc[o] = scb[o];
    bool hm = w > 0, hp = w < 255;
    #pragma unroll
    for (int i = 0; i < 8; ++i) {
        size_t base = (size_t)i * kFW + gi;
        float xm = hm ? b2f(in[base - str]) : 0.f;
        float x0 = b2f(in[base]);
        float xp = hp ? b2f(in[base + str]) : 0.f;
        #pragma unroll
        for (int o = 0; o < 8; ++o) {
            const float* wp = &scw[(o * 8 + i) * 3];
            acc[o] += wp[0] * xm + wp[1] * x0 + wp[2] * xp;
        }
    }
    #pragma unroll
    for (int o = 0; o < 8; ++o) out[(size_t)o * kFW + gi] = f2b(acc[o]);
}

// ================= fused 16->8 mix + conv (CA query path), T layout ===========
__global__ __launch_bounds__(256) void mixconv_kernel(const unsigned short* __restrict__ in,
                                                      const float* __restrict__ dw,
                                                      const float* __restrict__ cw,
                                                      const float* __restrict__ cb,
                                                      unsigned short* __restrict__ out) {
    __shared__ float sdw[128], scw[192], scb[8];
    int t = threadIdx.x;
    if (t < 128) sdw[t] = dw[t];
    if (t >= 128 && t < 136) scb[t - 128] = cb[t - 128];
    if (t < 192) scw[t] = cw[t];
    __syncthreads();
    int gi = blockIdx.x * 256 + t;
    int w = gi >> 9;
    bool hm = w > 0, hp = w < 255;
    float xc[16], xm[16], xp[16];
    #pragma unroll
    for (int cc = 0; cc < 16; ++cc) {
        size_t base = (size_t)cc * kFW + gi;
        xc[cc] = b2f(in[base]);
        xm[cc] = hm ? b2f(in[base - 512]) : 0.f;
        xp[cc] = hp ? b2f(in[base + 512]) : 0.f;
    }
    float mm[8], m0[8], mp[8];
    #pragma unroll
    for (int o = 0; o < 8; ++o) {
        float am = 0.f, a0 = 0.f, ap = 0.f;
        #pragma unroll
        for (int cc = 0; cc < 16; ++cc) {
            float wv = sdw[o * 16 + cc];
            am += wv * xm[cc]; a0 += wv * xc[cc]; ap += wv * xp[cc];
        }
        mm[o] = am; m0[o] = a0; mp[o] = ap;
    }
    #pragma unroll
    for (int o = 0; o < 8; ++o) {
        float acc = scb[o];
        #pragma unroll
        for (int i = 0; i < 8; ++i) {
            const float* wp = &scw[(o * 8 + i) * 3];
            acc += wp[0] * mm[i] + wp[1] * m0[i] + wp[2] * mp[i];
        }
        out[(size_t)o * kFW + gi] = f2b(acc);
    }
}

// ================= fused QK^T + scale + softmax ===============================
__global__ __launch_bounds__(256) void qk_softmax_kernel(
    const unsigned short* __restrict__ Qt, const unsigned short* __restrict__ Kt,
    float* __restrict__ S, unsigned short* __restrict__ P, float scale)
{
    __shared__ unsigned char lds[40960];
    __shared__ float smax[4][64];
    __shared__ float ssum[4][64];
    int t = threadIdx.x, lane = t & 63, wv = t >> 6;
    int l16 = lane & 15, l4 = lane >> 4;
    int swz = (lane & 7) << 4;
    int ch = blockIdx.y, c = ch >> 3, h = ch & 7;
    int bm = blockIdx.x * 64;
    const unsigned short* Qb = Qt + (size_t)c * kFW + h * 64;
    const unsigned short* Kb = Kt + (size_t)c * kFW + h * 64;
    float* Sb = S + (size_t)ch * 65536;
    unsigned short* Pb = P + (size_t)ch * 65536;

    #pragma unroll
    for (int it = 0; it < 2; ++it) {
        int idx = it * 256 + t; int r = idx >> 3, ck = idx & 7;
        s16x8 v = *(const s16x8*)(Qb + (size_t)(bm + r) * 512 + ck * 8);
        *(s16x8*)(&lds[r * 128 + ((ck * 16) ^ ((r & 7) << 4))]) = v;
    }
    #pragma unroll
    for (int it = 0; it < 8; ++it) {
        int idx = it * 256 + t; int r = idx >> 3, ck = idx & 7;
        s16x8 v = *(const s16x8*)(Kb + (size_t)r * 512 + ck * 8);
        *(s16x8*)(&lds[8192 + r * 128 + ((ck * 16) ^ ((r & 7) << 4))]) = v;
    }
    __syncthreads();
    f32x4 acc[4][4];
    #pragma unroll
    for (int i = 0; i < 4; ++i)
        #pragma unroll
        for (int j = 0; j < 4; ++j) acc[i][j] = (f32x4){0.f, 0.f, 0.f, 0.f};
    #pragma unroll
    for (int ks = 0; ks < 2; ++ks) {
        s16x8 af[4], bfr[4];
        #pragma unroll
        for (int mi = 0; mi < 4; ++mi)
            af[mi] = *(const s16x8*)(&lds[(mi * 16 + l16) * 128 + ((ks * 64 + l4 * 16) ^ swz)]);
        #pragma unroll
        for (int ni = 0; ni < 4; ++ni)
            bfr[ni] = *(const s16x8*)(&lds[8192 + (wv * 64 + ni * 16 + l16) * 128 + ((ks * 64 + l4 * 16) ^ swz)]);
        #pragma unroll
        for (int mi = 0; mi < 4; ++mi)
            #pragma unroll
            for (int ni = 0; ni < 4; ++ni)
                acc[mi][ni] = __builtin_amdgcn_mfma_f32_16x16x32_bf16(af[mi], bfr[ni], acc[mi][ni], 0, 0, 0);
    }
    #pragma unroll
    for (int mi = 0; mi < 4; ++mi)
        #pragma unroll
        for (int ni = 0; ni < 4; ++ni) {
            acc[mi][ni] *= scale;
            int col = wv * 64 + ni * 16 + l16;
            int row0 = bm + mi * 16 + l4 * 4;
            #pragma unroll
            for (int r = 0; r < 4; ++r)
                Sb[(size_t)(row0 + r) * 256 + col] = acc[mi][ni][r];
        }
    float rmax[4][4];
    #pragma unroll
    for (int mi = 0; mi < 4; ++mi)
        #pragma unroll
        for (int r = 0; r < 4; ++r)
            rmax[mi][r] = fmaxf(fmaxf(acc[mi][0][r], acc[mi][1][r]), fmaxf(acc[mi][2][r], acc[mi][3][r]));
    #pragma unroll
    for (int d = 1; d < 16; d <<= 1)
        #pragma unroll
        for (int mi = 0; mi < 4; ++mi)
            #pragma unroll
            for (int r = 0; r < 4; ++r)
                rmax[mi][r] = fmaxf(rmax[mi][r], __shfl_xor(rmax[mi][r], d));
    if (l16 == 0)
        #pragma unroll
        for (int mi = 0; mi < 4; ++mi)
            #pragma unroll
            for (int r = 0; r < 4; ++r)
                smax[wv][mi * 16 + l4 * 4 + r] = rmax[mi][r];
    __syncthreads();
    float rM[4][4], rsum[4][4];
    #pragma unroll
    for (int mi = 0; mi < 4; ++mi)
        #pragma unroll
        for (int r = 0; r < 4; ++r) {
            int row = mi * 16 + l4 * 4 + r;
            rM[mi][r] = fmaxf(fmaxf(smax[0][row], smax[1][row]), fmaxf(smax[2][row], smax[3][row]));
            rsum[mi][r] = 0.f;
        }
    #pragma unroll
    for (int mi = 0; mi < 4; ++mi)
        #pragma unroll
        for (int ni = 0; ni < 4; ++ni)
            #pragma unroll
            for (int r = 0; r < 4; ++r) {
                float e = __expf(acc[mi][ni][r] - rM[mi][r]);
                acc[mi][ni][r] = e;
                rsum[mi][r] += e;
            }
    #pragma unroll
    for (int d = 1; d < 16; d <<= 1)
        #pragma unroll
        for (int mi = 0; mi < 4; ++mi)
            #pragma unroll
            for (int r = 0; r < 4; ++r)
                rsum[mi][r] += __shfl_xor(rsum[mi][r], d);
    if (l16 == 0)
        #pragma unroll
        for (int mi = 0; mi < 4; ++mi)
            #pragma unroll
            for (int r = 0; r < 4; ++r)
                ssum[wv][mi * 16 + l4 * 4 + r] = rsum[mi][r];
    __syncthreads();
    #pragma unroll
    for (int mi = 0; mi < 4; ++mi)
        #pragma unroll
        for (int r = 0; r < 4; ++r) {
            int row = mi * 16 + l4 * 4 + r;
            float inv = 1.f / (ssum[0][row] + ssum[1][row] + ssum[2][row] + ssum[3][row]);
            #pragma unroll
            for (int ni = 0; ni < 4; ++ni)
                Pb[(size_t)(bm + row) * 256 + wv * 64 + ni * 16 + l16] = f2b(acc[mi][ni][r] * inv);
        }
}

// ================= FFN1: 24->24 mix + exact GELU, in place ====================
__global__ __launch_bounds__(256) void gelu24_kernel(unsigned short* __restrict__ z,
                                                     const float* __restrict__ dw) {
    __shared__ float sdw[576];
    int t = threadIdx.x;
    for (int i = t; i < 576; i += 256) sdw[i] = dw[i];
    __syncthreads();
    size_t gi = (size_t)blockIdx.x * 256 + t;
    const size_t CH = (size_t)256 * 2048;
    float xv[24];
    #pragma unroll
    for (int cc = 0; cc < 24; ++cc) xv[cc] = b2f(z[cc * CH + gi]);
    #pragma unroll
    for (int o = 0; o < 24; ++o) {
        float s = 0.f;
        #pragma unroll
        for (int cc = 0; cc < 24; ++cc) s += sdw[o * 24 + cc] * xv[cc];
        s = 0.5f * s * (1.0f + erff(s * 0.7071067811865475f));
        z[o * CH + gi] = f2b(s);
    }
}

// ================= FFN2 24->8 mix + residual ==================================
__global__ __launch_bounds__(256) void final_mix_add(const float* __restrict__ x,
                                                     const float* __restrict__ z2,
                                                     const float* __restrict__ dw,
                                                     float* __restrict__ out) {
    __shared__ float sdw[192];
    int t = threadIdx.x;
    if (t < 192) sdw[t] = dw[t];
    __syncthreads();
    int gi = blockIdx.x * 256 + t;
    float xv[24];
    #pragma unroll
    for (int cc = 0; cc < 24; ++cc) xv[cc] = z2[(size_t)cc * kFW + gi];
    #pragma unroll
    for (int o = 0; o < 8; ++o) {
        float s = 0.f;
        #pragma unroll
        for (int cc = 0; cc < 24; ++cc) s += sdw[o * 24 + cc] * xv[cc];
        out[(size_t)o * kFW + gi] = x[(size_t)o * kFW + gi] + s;
    }
}

// ================= launch =====================================================
extern "C" void kernel_launch(void* const* d_in, const int* in_sizes, int n_in,
                              void* d_out, int out_size, void* d_ws, size_t ws_size,
                              hipStream_t stream) {
    const float* x       = (const float*)d_in[0];
    const float* src     = (const float*)d_in[1];
    const float* ln_g    = (const float*)d_in[2];
    const float* ln_b    = (const float*)d_in[3];
    const float* sa_q_pw = (const float*)d_in[4];
    const float* sa_q_cw = (const float*)d_in[5];
    const float* sa_q_cb = (const float*)d_in[6];
    const float* sa_k_pw = (const float*)d_in[7];
    const float* sa_k_cw = (const float*)d_in[8];
    const float* sa_k_cb = (const float*)d_in[9];
    const float* sa_v_pw = (const float*)d_in[10];
    const float* sa_v_cw = (const float*)d_in[11];
    const float* sa_v_cb = (const float*)d_in[12];
    const float* sa_o_pw = (const float*)d_in[13];
    const float* ca_q_pw = (const float*)d_in[14];
    const float* ca_q_dw = (const float*)d_in[15];
    const float* ca_q_cw = (const float*)d_in[16];
    const float* ca_q_cb = (const float*)d_in[17];
    const float* ca_k_pw = (const float*)d_in[18];
    const float* ca_k_cw = (const float*)d_in[19];
    const float* ca_k_cb = (const float*)d_in[20];
    const float* ca_v_pw = (const float*)d_in[21];
    const float* ca_v_cw = (const float*)d_in[22];
    const float* ca_v_cb = (const float*)d_in[23];
    const float* ca_o_pw = (const float*)d_in[24];
    const float* ffn1_pw = (const float*)d_in[25];
    const float* ffn1_dw = (const float*)d_in[26];
    const float* ffn2_pw = (const float*)d_in[27];
    const float* ffn2_dw = (const float*)d_in[28];

    float* out  = (float*)d_out;
    float* qk1o = out + 1048576;
    float* qk2o = out + 1048576 + 4194304;

    unsigned char* ws = (unsigned char*)d_ws;
    unsigned short* CAT24  = (unsigned short*)(ws + 0);         // [24][256][512] (h|sa|ca)
    unsigned short* hTb    = CAT24;
    unsigned short* saTb   = CAT24 + 8 * (size_t)kFW;
    unsigned short* caTb   = CAT24 + 16 * (size_t)kFW;
    unsigned short* SRCT   = (unsigned short*)(ws + 6291456);
    unsigned short* preQ   = (unsigned short*)(ws + 8388608);
    unsigned short* preK   = (unsigned short*)(ws + 10485760);
    unsigned short* preVsa = (unsigned short*)(ws + 12582912);
    unsigned short* preKca = (unsigned short*)(ws + 14680064);
    unsigned short* preVca = (unsigned short*)(ws + 16777216);
    unsigned short* QT     = (unsigned short*)(ws + 18874368);
    unsigned short* KT     = (unsigned short*)(ws + 20971520);
    unsigned short* VNsa   = (unsigned short*)(ws + 23068672);
    unsigned short* KTca   = (unsigned short*)(ws + 25165824);
    unsigned short* VNca   = (unsigned short*)(ws + 27262976);
    unsigned short* PRE16  = (unsigned short*)(ws + 29360128);  // 4 MB
    unsigned short* QTca   = (unsigned short*)(ws + 33554432);
    unsigned short* ATTT   = (unsigned short*)(ws + 35651584);
    unsigned short* PB     = (unsigned short*)(ws + 37748736);  // 8 MB
    // FFN phase (attention scratch dead by then):
    unsigned short* Z0T    = (unsigned short*)(ws + 8388608);   // 24 MB [24][256][2048]
    float*          Z2     = (float*)(ws + 33554432);           // 12 MB [24][512][256]

    const float qscale = 0.044194173824159216f;   // 1/sqrt(512)
    dim3 blk(256);

    ln_t_kernel<<<128, blk, 0, stream>>>(x, ln_g, ln_b, hTb);
    tcvt_kernel<<<dim3(8, 8, 4), blk, 0, stream>>>(src, SRCT);

    // ---- batched projections: SA q,k,v + CA k,v ----
    WB5 p5;
    p5.s[0] = { sa_q_pw, hTb,  preQ,   2 };
    p5.s[1] = { sa_k_pw, hTb,  preK,   2 };
    p5.s[2] = { sa_v_pw, hTb,  preVsa, 1 };
    p5.s[3] = { ca_k_pw, SRCT, preKca, 2 };
    p5.s[4] = { ca_v_pw, SRCT, preVca, 1 };
    wgemm<<<dim3(32, 40), blk, 0, stream>>>(p5, 512, 512, 262144, kFW, kFW, 3);

    ConvArgs c5;
    c5.in[0] = preQ;   c5.out[0] = QT;   c5.cw[0] = sa_q_cw; c5.cb[0] = sa_q_cb; c5.mode[0] = 0;
    c5.in[1] = preK;   c5.out[1] = KT;   c5.cw[1] = sa_k_cw; c5.cb[1] = sa_k_cb; c5.mode[1] = 0;
    c5.in[2] = preVsa; c5.out[2] = VNsa; c5.cw[2] = sa_v_cw; c5.cb[2] = sa_v_cb; c5.mode[2] = 1;
    c5.in[3] = preKca; c5.out[3] = KTca; c5.cw[3] = ca_k_cw; c5.cb[3] = ca_k_cb; c5.mode[3] = 0;
    c5.in[4] = preVca; c5.out[4] = VNca; c5.cw[4] = ca_v_cw; c5.cb[4] = ca_v_cb; c5.mode[4] = 1;
    conv5_kernel<<<dim3(512, 5), blk, 0, stream>>>(c5);

    // ---- self attention ----
    qk_softmax_kernel<<<dim3(4, 64), blk, 0, stream>>>(QT, KT, qk1o, PB, qscale);
    gemm_mfma<1, 64><<<dim3(4, 64), blk, 0, stream>>>(PB, VNsa, ATTT, 256, 64, 256,
        524288, 65536, kFW, 16384, kFW, 64, 3, 256, 256, 512, 1.0f);
    WB5 so;
    so.s[0] = { sa_o_pw, ATTT, saTb, 2 };
    so.s[1] = so.s[0]; so.s[2] = so.s[0]; so.s[3] = so.s[0]; so.s[4] = so.s[0];
    wgemm<<<dim3(32, 8), blk, 0, stream>>>(so, 512, 512, 262144, kFW, kFW, 8);

    // ---- cross attention ----
    WB5 cq;
    cq.s[0] = { ca_q_pw, CAT24, PRE16, 2 };
    cq.s[1] = cq.s[0]; cq.s[2] = cq.s[0]; cq.s[3] = cq.s[0]; cq.s[4] = cq.s[0];
    wgemm<<<dim3(32, 16), blk, 0, stream>>>(cq, 512, 512, 262144, kFW, kFW, 8);
    mixconv_kernel<<<512, blk, 0, stream>>>(PRE16, ca_q_dw, ca_q_cw, ca_q_cb, QTca);

    qk_softmax_kernel<<<dim3(4, 64), blk, 0, stream>>>(QTca, KTca, qk2o, PB, qscale);
    gemm_mfma<1, 64><<<dim3(4, 64), blk, 0, stream>>>(PB, VNca, ATTT, 256, 64, 256,
        524288, 65536, kFW, 16384, kFW, 64, 3, 256, 256, 512, 1.0f);
    WB5 co;
    co.s[0] = { ca_o_pw, ATTT, caTb, 2 };
    co.s[1] = co.s[0]; co.s[2] = co.s[0]; co.s[3] = co.s[0]; co.s[4] = co.s[0];
    wgemm<<<dim3(32, 8), blk, 0, stream>>>(co, 512, 512, 262144, kFW, kFW, 8);

    // ---- FFN ----
    WB5 f1;
    f1.s[0] = { ffn1_pw, CAT24, Z0T, 2 };
    f1.s[1] = f1.s[0]; f1.s[2] = f1.s[0]; f1.s[3] = f1.s[0]; f1.s[4] = f1.s[0];
    wgemm<<<dim3(128, 24), blk, 0, stream>>>(f1, 2048, 512, 1048576, kFW, 524288, 8);
    gelu24_kernel<<<2048, blk, 0, stream>>>(Z0T, ffn1_dw);
    WB5 f2;
    f2.s[0] = { ffn2_pw, Z0T, Z2, 0 };
    f2.s[1] = f2.s[0]; f2.s[2] = f2.s[0]; f2.s[3] = f2.s[0]; f2.s[4] = f2.s[0];
    wgemm<<<dim3(32, 24), blk, 0, stream>>>(f2, 512, 2048, 1048576, 524288, 131072, 8);
    final_mix_add<<<512, blk, 0, stream>>>(x, Z2, ffn2_dw, out);
}

// Round 5
// 288.413 us; speedup vs baseline: 4.5681x; 1.1556x over previous
//
#include <hip/hip_runtime.h>
#include <math.h>

typedef __attribute__((ext_vector_type(4))) float f32x4;
typedef __attribute__((ext_vector_type(8))) short s16x8;
typedef __attribute__((ext_vector_type(4))) short s16x4;

__device__ __forceinline__ unsigned short f2b(float f) {
    union { float f; unsigned u; } v; v.f = f;
    unsigned r = v.u + 0x7fffu + ((v.u >> 16) & 1u);
    return (unsigned short)(r >> 16);
}
__device__ __forceinline__ float b2f(unsigned short u) {
    union { unsigned u; float f; } v; v.u = ((unsigned)u) << 16;
    return v.f;
}

constexpr int kF = 512;
constexpr int kW = 256;
constexpr int kFW = kF * kW;   // 131072

// ================= LayerNorm over f, output transposed bf16 [c][w][f] ==========
__global__ __launch_bounds__(256) void ln_t_kernel(const float* __restrict__ x,
                                                   const float* __restrict__ g,
                                                   const float* __restrict__ b,
                                                   unsigned short* __restrict__ hTb) {
    int c = blockIdx.x >> 4;
    int w0 = (blockIdx.x & 15) * 16;
    int t = threadIdx.x;
    int wi = t & 15, fg = t >> 4;
    const float* xb = x + (size_t)c * kFW + w0 + wi;
    float sum = 0.f, sum2 = 0.f;
    for (int j = 0; j < 32; ++j) {
        float v = xb[(size_t)(fg * 32 + j) * kW];
        sum += v; sum2 += v * v;
    }
    __shared__ float s1[16][16], s2[16][16];
    s1[fg][wi] = sum; s2[fg][wi] = sum2;
    __syncthreads();
    float ts = 0.f, tq = 0.f;
    #pragma unroll
    for (int j = 0; j < 16; ++j) { ts += s1[j][wi]; tq += s2[j][wi]; }
    float mu = ts * (1.0f / 512.0f);
    float rstd = rsqrtf(tq * (1.0f / 512.0f) - mu * mu + 1e-5f);
    const float* gc = g + c * kF + fg * 32;
    const float* bc = b + c * kF + fg * 32;
    unsigned short* ob = hTb + (size_t)c * kFW + (size_t)(w0 + wi) * kF + fg * 32;
    for (int j = 0; j < 32; j += 4) {
        float v0 = xb[(size_t)(fg * 32 + j + 0) * kW];
        float v1 = xb[(size_t)(fg * 32 + j + 1) * kW];
        float v2 = xb[(size_t)(fg * 32 + j + 2) * kW];
        float v3 = xb[(size_t)(fg * 32 + j + 3) * kW];
        s16x4 p = { (short)f2b((v0 - mu) * rstd * gc[j + 0] + bc[j + 0]),
                    (short)f2b((v1 - mu) * rstd * gc[j + 1] + bc[j + 1]),
                    (short)f2b((v2 - mu) * rstd * gc[j + 2] + bc[j + 2]),
                    (short)f2b((v3 - mu) * rstd * gc[j + 3] + bc[j + 3]) };
        *(s16x4*)(&ob[j]) = p;
    }
}

// ================= transpose + cvt: [c][f][w] f32 -> [c][w][f] bf16 ============
__global__ __launch_bounds__(256) void tcvt_kernel(const float* __restrict__ in,
                                                   unsigned short* __restrict__ out) {
    int c = blockIdx.x, f0 = blockIdx.y * 64, w0 = blockIdx.z * 64;
    __shared__ float tile[64][65];
    int t = threadIdx.x;
    int tw = t & 63, tf4 = t >> 6;
    for (int i = 0; i < 16; ++i) {
        int f = tf4 * 16 + i;
        tile[f][tw] = in[(size_t)c * kFW + (size_t)(f0 + f) * kW + w0 + tw];
    }
    __syncthreads();
    int w = t >> 2, fc = (t & 3) * 16;
    unsigned short* ob = out + (size_t)c * kFW + (size_t)(w0 + w) * kF + f0 + fc;
    for (int j = 0; j < 16; j += 4) {
        s16x4 p = { (short)f2b(tile[fc + j + 0][w]), (short)f2b(tile[fc + j + 1][w]),
                    (short)f2b(tile[fc + j + 2][w]), (short)f2b(tile[fc + j + 3][w]) };
        *(s16x4*)(&ob[j]) = p;
    }
}

// ================= full-N weight-streaming GEMM ===============================
// Block: 64 m x 256 n. Weights (f32) fetched EXACTLY ONCE (non-temporal, bypass
// L2 pollution). B (bf16 activations) staged per 64-k chunk in LDS (32 KB),
// async-split staging (issue loads early, ds_write after barrier).
// XCD decode: channel y pinned to XCD (id&7) so its B slice stays in that L2.
// omode: 0 = f32 [m][n] (+kz*c_split), 1 = bf16 [m][n], 2 = bf16 T [n][m]
struct WSeg { const float* A; const unsigned short* B; void* C; int omode; };
struct WB5 { WSeg s[5]; };

__global__ __launch_bounds__(256) void wgemm256(WB5 wb, int M, int K, int Klocal,
                                                long a_ch, long b_ch, long c_ch, long c_split,
                                                int segshift, int nm, int ksplit) {
    __shared__ unsigned short lds[16384];   // [256 n][64 k] swizzled
    int t = threadIdx.x, lane = t & 63, wv = t >> 6;
    int l16 = lane & 15, l4 = lane >> 4;

    int id = blockIdx.x;
    int r = id & 7, j = id >> 3;
    int per = nm * ksplit;
    int y = r + 8 * (j / per);
    int rem = j % per;
    int mt = rem % nm;
    int kz = rem / nm;
    int seg = y >> segshift, c = y & ((1 << segshift) - 1);
    WSeg sg = wb.s[seg];
    int bm = mt * 64;
    int kbase = kz * Klocal;

    const float* A = sg.A + (size_t)c * a_ch + kbase;
    const unsigned short* B = sg.B + (size_t)c * b_ch + kbase;
    const float* arow = A + (size_t)(bm + wv * 16 + l16) * K + l4 * 8;

    // staging assignment: thread t covers rows (t>>3)+it*32, k-slice (t&7)*8
    int srow = t >> 3, sck = t & 7;
    const unsigned short* bsrc = B + (size_t)srow * K + sck * 8;
    unsigned short* sdst = &lds[srow * 64 + ((sck * 8) ^ ((srow & 7) << 3))];

    s16x8 stg0, stg1, stg2, stg3, stg4, stg5, stg6, stg7;
    #define LOADSTG(c0) do { \
        const unsigned short* _b = bsrc + (size_t)(c0) * 64; \
        stg0 = *(const s16x8*)(_b); \
        stg1 = *(const s16x8*)(_b + (size_t)32 * K); \
        stg2 = *(const s16x8*)(_b + (size_t)64 * K); \
        stg3 = *(const s16x8*)(_b + (size_t)96 * K); \
        stg4 = *(const s16x8*)(_b + (size_t)128 * K); \
        stg5 = *(const s16x8*)(_b + (size_t)160 * K); \
        stg6 = *(const s16x8*)(_b + (size_t)192 * K); \
        stg7 = *(const s16x8*)(_b + (size_t)224 * K); \
    } while (0)
    #define WRITESTG() do { \
        *(s16x8*)(&sdst[0])     = stg0; \
        *(s16x8*)(&sdst[2048])  = stg1; \
        *(s16x8*)(&sdst[4096])  = stg2; \
        *(s16x8*)(&sdst[6144])  = stg3; \
        *(s16x8*)(&sdst[8192])  = stg4; \
        *(s16x8*)(&sdst[10240]) = stg5; \
        *(s16x8*)(&sdst[12288]) = stg6; \
        *(s16x8*)(&sdst[14336]) = stg7; \
    } while (0)

    f32x4 acc[16];
    #pragma unroll
    for (int i = 0; i < 16; ++i) acc[i] = (f32x4){0.f, 0.f, 0.f, 0.f};

    LOADSTG(0);
    WRITESTG();

    f32x4 pa0 = __builtin_nontemporal_load((const f32x4*)arow);
    f32x4 pa1 = __builtin_nontemporal_load((const f32x4*)(arow + 4));

    int nc = Klocal >> 6;
    for (int cch = 0; cch < nc; ++cch) {
        __syncthreads();                       // LDS chunk cch visible
        if (cch + 1 < nc) LOADSTG(cch + 1);    // issue early; hides under MFMA
        #pragma unroll
        for (int ks = 0; ks < 2; ++ks) {
            f32x4 c0 = pa0, c1 = pa1;
            int nk = cch * 64 + (ks + 1) * 32;
            if (nk < Klocal) {
                pa0 = __builtin_nontemporal_load((const f32x4*)(arow + nk));
                pa1 = __builtin_nontemporal_load((const f32x4*)(arow + nk + 4));
            }
            s16x8 af = { (short)f2b(c0.x), (short)f2b(c0.y), (short)f2b(c0.z), (short)f2b(c0.w),
                         (short)f2b(c1.x), (short)f2b(c1.y), (short)f2b(c1.z), (short)f2b(c1.w) };
            #pragma unroll
            for (int ni = 0; ni < 16; ++ni) {
                int rr = ni * 16 + l16;
                s16x8 bf = *(const s16x8*)(&lds[rr * 64 + (((ks * 32 + l4 * 8)) ^ ((rr & 7) << 3))]);
                acc[ni] = __builtin_amdgcn_mfma_f32_16x16x32_bf16(af, bf, acc[ni], 0, 0, 0);
            }
        }
        __syncthreads();                       // reads done
        if (cch + 1 < nc) WRITESTG();          // waits vmcnt internally
    }
    #undef LOADSTG
    #undef WRITESTG

    int m0 = bm + wv * 16 + l4 * 4;
    if (sg.omode == 2) {
        unsigned short* C = (unsigned short*)sg.C + (size_t)c * c_ch;
        #pragma unroll
        for (int ni = 0; ni < 16; ++ni) {
            int n = ni * 16 + l16;
            s16x4 pk = { (short)f2b(acc[ni][0]), (short)f2b(acc[ni][1]),
                         (short)f2b(acc[ni][2]), (short)f2b(acc[ni][3]) };
            *(s16x4*)(&C[(size_t)n * M + m0]) = pk;
        }
    } else if (sg.omode == 1) {
        unsigned short* C = (unsigned short*)sg.C + (size_t)c * c_ch;
        #pragma unroll
        for (int ni = 0; ni < 16; ++ni) {
            int n = ni * 16 + l16;
            #pragma unroll
            for (int rr = 0; rr < 4; ++rr)
                C[(size_t)(m0 + rr) * 256 + n] = f2b(acc[ni][rr]);
        }
    } else {
        float* C = (float*)sg.C + (size_t)c * c_ch + (size_t)kz * c_split;
        #pragma unroll
        for (int ni = 0; ni < 16; ++ni) {
            int n = ni * 16 + l16;
            #pragma unroll
            for (int rr = 0; rr < 4; ++rr)
                C[(size_t)(m0 + rr) * 256 + n] = acc[ni][rr];
        }
    }
}

// ================= bf16-A MFMA GEMM (PV only) =================================
template<int OMODE, int BN>
__global__ __launch_bounds__(256) void gemm_mfma(
    const unsigned short* __restrict__ Av, const unsigned short* __restrict__ B,
    void* __restrict__ Cv,
    int M, int N, int K,
    long a_hi, long a_lo, long b_hi, long b_lo, long c_hi, long c_lo,
    int bshift, int a_rs, int b_rs, int c_rs, float scale)
{
    constexpr int NF = BN / 64;
    constexpr int WN = BN / 4;
    __shared__ unsigned char lds[8192 + BN * 128];

    int t = threadIdx.x;
    int lane = t & 63, wv = t >> 6;
    int l16 = lane & 15, l4 = lane >> 4;
    int swz = (lane & 7) << 4;

    int by = blockIdx.y;
    int bhi = by >> bshift, blo = by & ((1 << bshift) - 1);
    int ntiles = N / BN;
    int bm = (blockIdx.x / ntiles) * 64;
    int bn = (blockIdx.x % ntiles) * BN;

    const unsigned short* Bp = B + (size_t)bhi * b_hi + (size_t)blo * b_lo + (size_t)bn * b_rs;
    const unsigned short* A = Av + (size_t)bhi * a_hi + (size_t)blo * a_lo;

    f32x4 acc[4][NF];
    #pragma unroll
    for (int i = 0; i < 4; ++i)
        #pragma unroll
        for (int j = 0; j < NF; ++j) acc[i][j] = (f32x4){0.f, 0.f, 0.f, 0.f};

    for (int k0 = 0; k0 < K; k0 += 64) {
        #pragma unroll
        for (int it = 0; it < 2; ++it) {
            int idx = it * 256 + t;
            int rr = idx >> 3, ck = idx & 7;
            s16x8 v = *(const s16x8*)(A + (size_t)(bm + rr) * a_rs + k0 + ck * 8);
            int off = rr * 128 + ((ck * 16) ^ ((rr & 7) << 4));
            *(s16x8*)(&lds[off]) = v;
        }
        #pragma unroll
        for (int it = 0; it < BN / 32; ++it) {
            int idx = it * 256 + t;
            int rr = idx >> 3, ck = idx & 7;
            s16x8 v = *(const s16x8*)(Bp + (size_t)rr * b_rs + k0 + ck * 8);
            int off = 8192 + rr * 128 + ((ck * 16) ^ ((rr & 7) << 4));
            *(s16x8*)(&lds[off]) = v;
        }
        __syncthreads();
        #pragma unroll
        for (int ks = 0; ks < 2; ++ks) {
            s16x8 af[4], bfr[NF];
            #pragma unroll
            for (int mi = 0; mi < 4; ++mi)
                af[mi] = *(const s16x8*)(&lds[(mi * 16 + l16) * 128 + ((ks * 64 + l4 * 16) ^ swz)]);
            #pragma unroll
            for (int ni = 0; ni < NF; ++ni)
                bfr[ni] = *(const s16x8*)(&lds[8192 + (wv * WN + ni * 16 + l16) * 128 + ((ks * 64 + l4 * 16) ^ swz)]);
            #pragma unroll
            for (int mi = 0; mi < 4; ++mi)
                #pragma unroll
                for (int ni = 0; ni < NF; ++ni)
                    acc[mi][ni] = __builtin_amdgcn_mfma_f32_16x16x32_bf16(af[mi], bfr[ni], acc[mi][ni], 0, 0, 0);
        }
        __syncthreads();
    }

    unsigned short* C = (unsigned short*)Cv + (size_t)bhi * c_hi + (size_t)blo * c_lo;
    #pragma unroll
    for (int mi = 0; mi < 4; ++mi)
        #pragma unroll
        for (int ni = 0; ni < NF; ++ni) {
            int n = bn + wv * WN + ni * 16 + l16;
            int m0 = bm + mi * 16 + l4 * 4;
            #pragma unroll
            for (int rr = 0; rr < 4; ++rr)
                C[(size_t)(m0 + rr) * c_rs + n] = f2b(acc[mi][ni][rr] * scale);
        }
}

// ================= batched conv (1,3) + 8->8 mix, 5 groups =====================
struct ConvArgs {
    const unsigned short* in[5];
    unsigned short* out[5];
    const float* cw[5];
    const float* cb[5];
    int mode[5];
};

__global__ __launch_bounds__(256) void conv5_kernel(ConvArgs a) {
    int g = blockIdx.y;
    __shared__ float scw[192]; __shared__ float scb[8];
    int t = threadIdx.x;
    if (t < 192) scw[t] = a.cw[g][t];
    if (t >= 192 && t < 200) scb[t - 192] = a.cb[g][t - 192];
    __syncthreads();
    const unsigned short* in = a.in[g];
    unsigned short* out = a.out[g];
    int gi = blockIdx.x * 256 + t;
    int mode = a.mode[g];
    int w = mode ? (gi & 255) : (gi >> 9);
    int str = mode ? 1 : 512;
    float acc[8];
    #pragma unroll
    for (int o = 0; o < 8; ++o) acc[o] = scb[o];
    bool hm = w > 0, hp = w < 255;
    #pragma unroll
    for (int i = 0; i < 8; ++i) {
        size_t base = (size_t)i * kFW + gi;
        float xm = hm ? b2f(in[base - str]) : 0.f;
        float x0 = b2f(in[base]);
        float xp = hp ? b2f(in[base + str]) : 0.f;
        #pragma unroll
        for (int o = 0; o < 8; ++o) {
            const float* wp = &scw[(o * 8 + i) * 3];
            acc[o] += wp[0] * xm + wp[1] * x0 + wp[2] * xp;
        }
    }
    #pragma unroll
    for (int o = 0; o < 8; ++o) out[(size_t)o * kFW + gi] = f2b(acc[o]);
}

// ================= fused 16->8 mix + conv (CA query path), T layout ===========
__global__ __launch_bounds__(256) void mixconv_kernel(const unsigned short* __restrict__ in,
                                                      const float* __restrict__ dw,
                                                      const float* __restrict__ cw,
                                                      const float* __restrict__ cb,
                                                      unsigned short* __restrict__ out) {
    __shared__ float sdw[128], scw[192], scb[8];
    int t = threadIdx.x;
    if (t < 128) sdw[t] = dw[t];
    if (t >= 128 && t < 136) scb[t - 128] = cb[t - 128];
    if (t < 192) scw[t] = cw[t];
    __syncthreads();
    int gi = blockIdx.x * 256 + t;
    int w = gi >> 9;
    bool hm = w > 0, hp = w < 255;
    float xc[16], xm[16], xp[16];
    #pragma unroll
    for (int cc = 0; cc < 16; ++cc) {
        size_t base = (size_t)cc * kFW + gi;
        xc[cc] = b2f(in[base]);
        xm[cc] = hm ? b2f(in[base - 512]) : 0.f;
        xp[cc] = hp ? b2f(in[base + 512]) : 0.f;
    }
    float mm[8], m0[8], mp[8];
    #pragma unroll
    for (int o = 0; o < 8; ++o) {
        float am = 0.f, a0 = 0.f, ap = 0.f;
        #pragma unroll
        for (int cc = 0; cc < 16; ++cc) {
            float wv = sdw[o * 16 + cc];
            am += wv * xm[cc]; a0 += wv * xc[cc]; ap += wv * xp[cc];
        }
        mm[o] = am; m0[o] = a0; mp[o] = ap;
    }
    #pragma unroll
    for (int o = 0; o < 8; ++o) {
        float acc = scb[o];
        #pragma unroll
        for (int i = 0; i < 8; ++i) {
            const float* wp = &scw[(o * 8 + i) * 3];
            acc += wp[0] * mm[i] + wp[1] * m0[i] + wp[2] * mp[i];
        }
        out[(size_t)o * kFW + gi] = f2b(acc);
    }
}

// ================= fused QK^T + scale + softmax ===============================
__global__ __launch_bounds__(256) void qk_softmax_kernel(
    const unsigned short* __restrict__ Qt, const unsigned short* __restrict__ Kt,
    float* __restrict__ S, unsigned short* __restrict__ P, float scale)
{
    __shared__ unsigned char lds[40960];
    __shared__ float smax[4][64];
    __shared__ float ssum[4][64];
    int t = threadIdx.x, lane = t & 63, wv = t >> 6;
    int l16 = lane & 15, l4 = lane >> 4;
    int swz = (lane & 7) << 4;
    int ch = blockIdx.y, c = ch >> 3, h = ch & 7;
    int bm = blockIdx.x * 64;
    const unsigned short* Qb = Qt + (size_t)c * kFW + h * 64;
    const unsigned short* Kb = Kt + (size_t)c * kFW + h * 64;
    float* Sb = S + (size_t)ch * 65536;
    unsigned short* Pb = P + (size_t)ch * 65536;

    #pragma unroll
    for (int it = 0; it < 2; ++it) {
        int idx = it * 256 + t; int rr = idx >> 3, ck = idx & 7;
        s16x8 v = *(const s16x8*)(Qb + (size_t)(bm + rr) * 512 + ck * 8);
        *(s16x8*)(&lds[rr * 128 + ((ck * 16) ^ ((rr & 7) << 4))]) = v;
    }
    #pragma unroll
    for (int it = 0; it < 8; ++it) {
        int idx = it * 256 + t; int rr = idx >> 3, ck = idx & 7;
        s16x8 v = *(const s16x8*)(Kb + (size_t)rr * 512 + ck * 8);
        *(s16x8*)(&lds[8192 + rr * 128 + ((ck * 16) ^ ((rr & 7) << 4))]) = v;
    }
    __syncthreads();
    f32x4 acc[4][4];
    #pragma unroll
    for (int i = 0; i < 4; ++i)
        #pragma unroll
        for (int j = 0; j < 4; ++j) acc[i][j] = (f32x4){0.f, 0.f, 0.f, 0.f};
    #pragma unroll
    for (int ks = 0; ks < 2; ++ks) {
        s16x8 af[4], bfr[4];
        #pragma unroll
        for (int mi = 0; mi < 4; ++mi)
            af[mi] = *(const s16x8*)(&lds[(mi * 16 + l16) * 128 + ((ks * 64 + l4 * 16) ^ swz)]);
        #pragma unroll
        for (int ni = 0; ni < 4; ++ni)
            bfr[ni] = *(const s16x8*)(&lds[8192 + (wv * 64 + ni * 16 + l16) * 128 + ((ks * 64 + l4 * 16) ^ swz)]);
        #pragma unroll
        for (int mi = 0; mi < 4; ++mi)
            #pragma unroll
            for (int ni = 0; ni < 4; ++ni)
                acc[mi][ni] = __builtin_amdgcn_mfma_f32_16x16x32_bf16(af[mi], bfr[ni], acc[mi][ni], 0, 0, 0);
    }
    #pragma unroll
    for (int mi = 0; mi < 4; ++mi)
        #pragma unroll
        for (int ni = 0; ni < 4; ++ni) {
            acc[mi][ni] *= scale;
            int col = wv * 64 + ni * 16 + l16;
            int row0 = bm + mi * 16 + l4 * 4;
            #pragma unroll
            for (int rr = 0; rr < 4; ++rr)
                Sb[(size_t)(row0 + rr) * 256 + col] = acc[mi][ni][rr];
        }
    float rmax[4][4];
    #pragma unroll
    for (int mi = 0; mi < 4; ++mi)
        #pragma unroll
        for (int rr = 0; rr < 4; ++rr)
            rmax[mi][rr] = fmaxf(fmaxf(acc[mi][0][rr], acc[mi][1][rr]), fmaxf(acc[mi][2][rr], acc[mi][3][rr]));
    #pragma unroll
    for (int d = 1; d < 16; d <<= 1)
        #pragma unroll
        for (int mi = 0; mi < 4; ++mi)
            #pragma unroll
            for (int rr = 0; rr < 4; ++rr)
                rmax[mi][rr] = fmaxf(rmax[mi][rr], __shfl_xor(rmax[mi][rr], d));
    if (l16 == 0)
        #pragma unroll
        for (int mi = 0; mi < 4; ++mi)
            #pragma unroll
            for (int rr = 0; rr < 4; ++rr)
                smax[wv][mi * 16 + l4 * 4 + rr] = rmax[mi][rr];
    __syncthreads();
    float rM[4][4], rsum[4][4];
    #pragma unroll
    for (int mi = 0; mi < 4; ++mi)
        #pragma unroll
        for (int rr = 0; rr < 4; ++rr) {
            int row = mi * 16 + l4 * 4 + rr;
            rM[mi][rr] = fmaxf(fmaxf(smax[0][row], smax[1][row]), fmaxf(smax[2][row], smax[3][row]));
            rsum[mi][rr] = 0.f;
        }
    #pragma unroll
    for (int mi = 0; mi < 4; ++mi)
        #pragma unroll
        for (int ni = 0; ni < 4; ++ni)
            #pragma unroll
            for (int rr = 0; rr < 4; ++rr) {
                float e = __expf(acc[mi][ni][rr] - rM[mi][rr]);
                acc[mi][ni][rr] = e;
                rsum[mi][rr] += e;
            }
    #pragma unroll
    for (int d = 1; d < 16; d <<= 1)
        #pragma unroll
        for (int mi = 0; mi < 4; ++mi)
            #pragma unroll
            for (int rr = 0; rr < 4; ++rr)
                rsum[mi][rr] += __shfl_xor(rsum[mi][rr], d);
    if (l16 == 0)
        #pragma unroll
        for (int mi = 0; mi < 4; ++mi)
            #pragma unroll
            for (int rr = 0; rr < 4; ++rr)
                ssum[wv][mi * 16 + l4 * 4 + rr] = rsum[mi][rr];
    __syncthreads();
    #pragma unroll
    for (int mi = 0; mi < 4; ++mi)
        #pragma unroll
        for (int rr = 0; rr < 4; ++rr) {
            int row = mi * 16 + l4 * 4 + rr;
            float inv = 1.f / (ssum[0][row] + ssum[1][row] + ssum[2][row] + ssum[3][row]);
            #pragma unroll
            for (int ni = 0; ni < 4; ++ni)
                Pb[(size_t)(bm + row) * 256 + wv * 64 + ni * 16 + l16] = f2b(acc[mi][ni][rr] * inv);
        }
}

// ================= FFN1: 24->24 mix + exact GELU, in place ====================
__global__ __launch_bounds__(256) void gelu24_kernel(unsigned short* __restrict__ z,
                                                     const float* __restrict__ dw) {
    __shared__ float sdw[576];
    int t = threadIdx.x;
    for (int i = t; i < 576; i += 256) sdw[i] = dw[i];
    __syncthreads();
    size_t gi = (size_t)blockIdx.x * 256 + t;
    const size_t CH = (size_t)256 * 2048;
    float xv[24];
    #pragma unroll
    for (int cc = 0; cc < 24; ++cc) xv[cc] = b2f(z[cc * CH + gi]);
    #pragma unroll
    for (int o = 0; o < 24; ++o) {
        float s = 0.f;
        #pragma unroll
        for (int cc = 0; cc < 24; ++cc) s += sdw[o * 24 + cc] * xv[cc];
        s = 0.5f * s * (1.0f + erff(s * 0.7071067811865475f));
        z[o * CH + gi] = f2b(s);
    }
}

// ================= FFN2 reduce(2 partials) + 24->8 mix + residual =============
__global__ __launch_bounds__(256) void final_mix_add2(const float* __restrict__ x,
                                                      const float* __restrict__ z2,
                                                      const float* __restrict__ dw,
                                                      float* __restrict__ out) {
    __shared__ float sdw[192];
    int t = threadIdx.x;
    if (t < 192) sdw[t] = dw[t];
    __syncthreads();
    int gi = blockIdx.x * 256 + t;
    const size_t PSZ = (size_t)24 * kFW;
    float xv[24];
    #pragma unroll
    for (int cc = 0; cc < 24; ++cc) {
        size_t o = (size_t)cc * kFW + gi;
        xv[cc] = z2[o] + z2[PSZ + o];
    }
    #pragma unroll
    for (int o = 0; o < 8; ++o) {
        float s = 0.f;
        #pragma unroll
        for (int cc = 0; cc < 24; ++cc) s += sdw[o * 24 + cc] * xv[cc];
        out[(size_t)o * kFW + gi] = x[(size_t)o * kFW + gi] + s;
    }
}

// ================= launch =====================================================
extern "C" void kernel_launch(void* const* d_in, const int* in_sizes, int n_in,
                              void* d_out, int out_size, void* d_ws, size_t ws_size,
                              hipStream_t stream) {
    const float* x       = (const float*)d_in[0];
    const float* src     = (const float*)d_in[1];
    const float* ln_g    = (const float*)d_in[2];
    const float* ln_b    = (const float*)d_in[3];
    const float* sa_q_pw = (const float*)d_in[4];
    const float* sa_q_cw = (const float*)d_in[5];
    const float* sa_q_cb = (const float*)d_in[6];
    const float* sa_k_pw = (const float*)d_in[7];
    const float* sa_k_cw = (const float*)d_in[8];
    const float* sa_k_cb = (const float*)d_in[9];
    const float* sa_v_pw = (const float*)d_in[10];
    const float* sa_v_cw = (const float*)d_in[11];
    const float* sa_v_cb = (const float*)d_in[12];
    const float* sa_o_pw = (const float*)d_in[13];
    const float* ca_q_pw = (const float*)d_in[14];
    const float* ca_q_dw = (const float*)d_in[15];
    const float* ca_q_cw = (const float*)d_in[16];
    const float* ca_q_cb = (const float*)d_in[17];
    const float* ca_k_pw = (const float*)d_in[18];
    const float* ca_k_cw = (const float*)d_in[19];
    const float* ca_k_cb = (const float*)d_in[20];
    const float* ca_v_pw = (const float*)d_in[21];
    const float* ca_v_cw = (const float*)d_in[22];
    const float* ca_v_cb = (const float*)d_in[23];
    const float* ca_o_pw = (const float*)d_in[24];
    const float* ffn1_pw = (const float*)d_in[25];
    const float* ffn1_dw = (const float*)d_in[26];
    const float* ffn2_pw = (const float*)d_in[27];
    const float* ffn2_dw = (const float*)d_in[28];

    float* out  = (float*)d_out;
    float* qk1o = out + 1048576;
    float* qk2o = out + 1048576 + 4194304;

    unsigned char* ws = (unsigned char*)d_ws;
    unsigned short* CAT24  = (unsigned short*)(ws + 0);
    unsigned short* hTb    = CAT24;
    unsigned short* saTb   = CAT24 + 8 * (size_t)kFW;
    unsigned short* caTb   = CAT24 + 16 * (size_t)kFW;
    unsigned short* SRCT   = (unsigned short*)(ws + 6291456);
    unsigned short* preQ   = (unsigned short*)(ws + 8388608);
    unsigned short* preK   = (unsigned short*)(ws + 10485760);
    unsigned short* preVsa = (unsigned short*)(ws + 12582912);
    unsigned short* preKca = (unsigned short*)(ws + 14680064);
    unsigned short* preVca = (unsigned short*)(ws + 16777216);
    unsigned short* QT     = (unsigned short*)(ws + 18874368);
    unsigned short* KT     = (unsigned short*)(ws + 20971520);
    unsigned short* VNsa   = (unsigned short*)(ws + 23068672);
    unsigned short* KTca   = (unsigned short*)(ws + 25165824);
    unsigned short* VNca   = (unsigned short*)(ws + 27262976);
    unsigned short* PRE16  = (unsigned short*)(ws + 29360128);
    unsigned short* QTca   = (unsigned short*)(ws + 33554432);
    unsigned short* ATTT   = (unsigned short*)(ws + 35651584);
    unsigned short* PB     = (unsigned short*)(ws + 37748736);
    // FFN phase (attention scratch dead by then):
    unsigned short* Z0T    = (unsigned short*)(ws + 8388608);   // 25 MB [24][256][2048]
    float*          Z2P    = (float*)(ws + 33554432);           // 2 x 12.6 MB partials

    const float qscale = 0.044194173824159216f;   // 1/sqrt(512)
    dim3 blk(256);

    ln_t_kernel<<<128, blk, 0, stream>>>(x, ln_g, ln_b, hTb);
    tcvt_kernel<<<dim3(8, 8, 4), blk, 0, stream>>>(src, SRCT);

    // ---- batched projections: SA q,k,v + CA k,v (ny=40, nm=8) ----
    WB5 p5;
    p5.s[0] = { sa_q_pw, hTb,  preQ,   2 };
    p5.s[1] = { sa_k_pw, hTb,  preK,   2 };
    p5.s[2] = { sa_v_pw, hTb,  preVsa, 1 };
    p5.s[3] = { ca_k_pw, SRCT, preKca, 2 };
    p5.s[4] = { ca_v_pw, SRCT, preVca, 1 };
    wgemm256<<<dim3(320), blk, 0, stream>>>(p5, 512, 512, 512, 262144, kFW, kFW, 0, 3, 8, 1);

    ConvArgs c5;
    c5.in[0] = preQ;   c5.out[0] = QT;   c5.cw[0] = sa_q_cw; c5.cb[0] = sa_q_cb; c5.mode[0] = 0;
    c5.in[1] = preK;   c5.out[1] = KT;   c5.cw[1] = sa_k_cw; c5.cb[1] = sa_k_cb; c5.mode[1] = 0;
    c5.in[2] = preVsa; c5.out[2] = VNsa; c5.cw[2] = sa_v_cw; c5.cb[2] = sa_v_cb; c5.mode[2] = 1;
    c5.in[3] = preKca; c5.out[3] = KTca; c5.cw[3] = ca_k_cw; c5.cb[3] = ca_k_cb; c5.mode[3] = 0;
    c5.in[4] = preVca; c5.out[4] = VNca; c5.cw[4] = ca_v_cw; c5.cb[4] = ca_v_cb; c5.mode[4] = 1;
    conv5_kernel<<<dim3(512, 5), blk, 0, stream>>>(c5);

    // ---- self attention ----
    qk_softmax_kernel<<<dim3(4, 64), blk, 0, stream>>>(QT, KT, qk1o, PB, qscale);
    gemm_mfma<1, 64><<<dim3(4, 64), blk, 0, stream>>>(PB, VNsa, ATTT, 256, 64, 256,
        524288, 65536, kFW, 16384, kFW, 64, 3, 256, 256, 512, 1.0f);
    WB5 so;
    so.s[0] = { sa_o_pw, ATTT, saTb, 2 };
    so.s[1] = so.s[0]; so.s[2] = so.s[0]; so.s[3] = so.s[0]; so.s[4] = so.s[0];
    wgemm256<<<dim3(64), blk, 0, stream>>>(so, 512, 512, 512, 262144, kFW, kFW, 0, 8, 8, 1);

    // ---- cross attention ----
    WB5 cq;
    cq.s[0] = { ca_q_pw, CAT24, PRE16, 2 };
    cq.s[1] = cq.s[0]; cq.s[2] = cq.s[0]; cq.s[3] = cq.s[0]; cq.s[4] = cq.s[0];
    wgemm256<<<dim3(128), blk, 0, stream>>>(cq, 512, 512, 512, 262144, kFW, kFW, 0, 8, 8, 1);
    mixconv_kernel<<<512, blk, 0, stream>>>(PRE16, ca_q_dw, ca_q_cw, ca_q_cb, QTca);

    qk_softmax_kernel<<<dim3(4, 64), blk, 0, stream>>>(QTca, KTca, qk2o, PB, qscale);
    gemm_mfma<1, 64><<<dim3(4, 64), blk, 0, stream>>>(PB, VNca, ATTT, 256, 64, 256,
        524288, 65536, kFW, 16384, kFW, 64, 3, 256, 256, 512, 1.0f);
    WB5 co;
    co.s[0] = { ca_o_pw, ATTT, caTb, 2 };
    co.s[1] = co.s[0]; co.s[2] = co.s[0]; co.s[3] = co.s[0]; co.s[4] = co.s[0];
    wgemm256<<<dim3(64), blk, 0, stream>>>(co, 512, 512, 512, 262144, kFW, kFW, 0, 8, 8, 1);

    // ---- FFN ----
    WB5 f1;
    f1.s[0] = { ffn1_pw, CAT24, Z0T, 2 };
    f1.s[1] = f1.s[0]; f1.s[2] = f1.s[0]; f1.s[3] = f1.s[0]; f1.s[4] = f1.s[0];
    wgemm256<<<dim3(768), blk, 0, stream>>>(f1, 2048, 512, 512, 1048576, kFW, 524288, 0, 8, 32, 1);
    gelu24_kernel<<<2048, blk, 0, stream>>>(Z0T, ffn1_dw);
    WB5 f2;
    f2.s[0] = { ffn2_pw, Z0T, Z2P, 0 };
    f2.s[1] = f2.s[0]; f2.s[2] = f2.s[0]; f2.s[3] = f2.s[0]; f2.s[4] = f2.s[0];
    wgemm256<<<dim3(384), blk, 0, stream>>>(f2, 512, 2048, 1024, 1048576, 524288, kFW, 3145728, 8, 8, 2);
    final_mix_add2<<<512, blk, 0, stream>>>(x, Z2P, ffn2_dw, out);
}